// Round 7
// baseline (1974.812 us; speedup 1.0000x reference)
//
#include <hip/hip_runtime.h>
#include <cstdint>
#include <cstddef>

#define BATCH       65536
#define LDSW        36          // padded LDS row stride for tiny-kernel matrices
#define NCHEB       16          // Chebyshev terms for log on [CALPHA, CBETA] (spectrum-tight)
#define CALPHA      0.28f       // lambda_min(x) >= 0.5 by construction; whitened >= ~0.32
#define CBETA       4.6f        // MP+TW bound 5.1 / mean ~1.25 => <= ~4.3
#define NS_ITERS    6           // Newton-Schulz sqrt iterations
#define EXP_TERMS   8           // Taylor terms for matrix exp (||pL|| <= ~0.8)
#define GRID_B      4096        // 16 blocks/CU target, bounds(64,3)
#define GRID_C      4096
#define GRID_D      4096

// ws float offsets
#define OFF_MEAN0   0
#define OFF_INVS0   1024
#define OFF_S0      2048
#define OFF_LOGAVG  3072
#define OFF_INVS    4096
#define OFF_SSQRT   5120
#define OFF_VAR     6144
#define OFF_P       6145
#define OFF_CHEB    6152        // NCHEB floats

typedef float (*LdsMat)[LDSW];
typedef __attribute__((ext_vector_type(8))) short          short8;
typedef __attribute__((ext_vector_type(4))) float          f32x4;
typedef unsigned short u16t;
typedef unsigned int   u32t;

#define MFMA16(a, b, c) __builtin_amdgcn_mfma_f32_16x16x32_bf16((a), (b), (c), 0, 0, 0)

// ---------------- bf16 pack / split helpers (perm-based, round-4-proven) ----------------
__device__ __forceinline__ u32t pack2_rn(float a, float b) {
  u32t ua = __float_as_uint(a) + 0x8000u;
  u32t ub = __float_as_uint(b) + 0x8000u;
  return __builtin_amdgcn_perm(ub, ua, 0x07060302u);
}
__device__ __forceinline__ void split2(float a, float b, u32t& hw, u32t& lw) {
  u32t ua = __float_as_uint(a) + 0x8000u;
  u32t ub = __float_as_uint(b) + 0x8000u;
  hw = __builtin_amdgcn_perm(ub, ua, 0x07060302u);
  float ra = a - __uint_as_float(ua & 0xFFFF0000u);
  float rb = b - __uint_as_float(ub & 0xFFFF0000u);
  lw = __builtin_amdgcn_perm(__float_as_uint(rb), __float_as_uint(ra), 0x07060302u);
}

// Staged matrices: u16 [32][40] col-major (G[col][row] = bf16 of M[row][col]).
__device__ __forceinline__ short8 fragr(const u16t (*G)[40], int t, int c15, int g) {
  return *reinterpret_cast<const short8*>(&G[16 * t + c15][8 * g]);
}
__device__ __forceinline__ void stg_single(u16t (*G)[40], int col, int row, f32x4 v) {
  uint2 w; w.x = pack2_rn(v[0], v[1]); w.y = pack2_rn(v[2], v[3]);
  *reinterpret_cast<uint2*>(&G[col][row]) = w;
}
__device__ __forceinline__ void stg_split(u16t (*Gh)[40], u16t (*Gl)[40], int col, int row, f32x4 v) {
  u32t h0, l0, h1, l1;
  split2(v[0], v[1], h0, l0);
  split2(v[2], v[3], h1, l1);
  uint2 hv; hv.x = h0; hv.y = h1;
  uint2 lv; lv.x = l0; lv.y = l1;
  *reinterpret_cast<uint2*>(&Gh[col][row]) = hv;
  *reinterpret_cast<uint2*>(&Gl[col][row]) = lv;
}
// split two pre-loaded float4 (8 consecutive values of one symmetric-matrix row slice)
__device__ __forceinline__ void split8regs(float4 a, float4 b, float mul, short8& hi, short8& lo) {
  u32t h0, l0, h1, l1, h2, l2, h3, l3;
  split2(a.x * mul, a.y * mul, h0, l0);
  split2(a.z * mul, a.w * mul, h1, l1);
  split2(b.x * mul, b.y * mul, h2, l2);
  split2(b.z * mul, b.w * mul, h3, l3);
  union { uint4 u; short8 s; } uh, ul;
  uh.u.x = h0; uh.u.y = h1; uh.u.z = h2; uh.u.w = h3;
  ul.u.x = l0; ul.u.y = l1; ul.u.z = l2; ul.u.w = l3;
  hi = uh.s; lo = ul.s;
}

// scalar split for cold-path frag loads
__device__ __forceinline__ void splitf(float a, u16t& h, u16t& l) {
  unsigned u  = __float_as_uint(a);
  unsigned uh = (u + 0x8000u) & 0xFFFF0000u;
  float    r  = a - __uint_as_float(uh);
  unsigned ul = __float_as_uint(r) + 0x8000u;
  h = (u16t)(uh >> 16);
  l = (u16t)(ul >> 16);
}
__device__ __forceinline__ void load_sym_frags(const float* base, int c15, int g,
                                               short8* Fh, short8* Fl) {
#pragma unroll
  for (int t = 0; t < 2; ++t) {
    const float* sp = base + (16 * t + c15) * 32 + 8 * g;
    short8 hh, ll;
#pragma unroll
    for (int j = 0; j < 8; ++j) {
      u16t h, l;
      splitf(sp[j], h, l);
      hh[j] = (short)h;
      ll[j] = (short)l;
    }
    Fh[t] = hh;
    Fl[t] = ll;
  }
}

// ---------------- MFMA whiten + forward-Chebyshev log core (round-4 math) ----------------
// L = cheb_log( GSC*(S x S) - MSH*I ).  X A-frags pre-split by the caller (prefetch).
template <bool ACCUM>
__device__ __forceinline__ void whiten_cheb(
    const short8* Xa_h, const short8* Xa_l, const short8* S_h, const short8* S_l,
    u16t (*H)[40], u16t (*Lo)[40], u16t (*Bu)[40],
    const float* __restrict__ cof, int g, int c15, const f32x4& dg4, f32x4 (&L)[2][2]) {
  const f32x4 z4 = {0.f, 0.f, 0.f, 0.f};
  // 2. V2 = X * S  -> split staged into H/Lo
  f32x4 acc[2][2];
#pragma unroll
  for (int i = 0; i < 2; ++i)
#pragma unroll
    for (int j = 0; j < 2; ++j) {
      f32x4 a = z4;
      a = MFMA16(Xa_l[i], S_h[j], a);
      a = MFMA16(Xa_h[i], S_l[j], a);
      a = MFMA16(Xa_h[i], S_h[j], a);
      acc[i][j] = a;
    }
#pragma unroll
  for (int i = 0; i < 2; ++i)
#pragma unroll
    for (int j = 0; j < 2; ++j)
      stg_split(H, Lo, 16 * j + c15, 16 * i + 4 * g, acc[i][j]);
  __syncthreads();
  short8 Vb_h[2], Vb_l[2];
#pragma unroll
  for (int j = 0; j < 2; ++j) {
    Vb_h[j] = fragr(H, j, c15, g);
    Vb_l[j] = fragr(Lo, j, c15, g);
  }
  // 3. Y = S * V2 ; Ytilde = GSC*Y - MSH*I  (= T1)
#pragma unroll
  for (int j = 0; j < 2; ++j)
#pragma unroll
    for (int i = 0; i < 2; ++i) {
      f32x4 a = z4;
      a = MFMA16(S_l[i], Vb_h[j], a);
      a = MFMA16(S_h[i], Vb_l[j], a);
      a = MFMA16(S_h[i], Vb_h[j], a);
      acc[i][j] = a;
    }
  const float GSC = 2.f / (CBETA - CALPHA);
  const float MSH = (CALPHA + CBETA) / (CBETA - CALPHA);
  const float c0 = cof[0], c1 = cof[1];
  f32x4 nTm2[2][2], accB[2][2];
#pragma unroll
  for (int i = 0; i < 2; ++i)
#pragma unroll
    for (int j = 0; j < 2; ++j)
#pragma unroll
      for (int r = 0; r < 4; ++r) {
        float dgf = (i == j) ? dg4[r] : 0.f;
        float yt  = fmaf(acc[i][j][r], GSC, -MSH * dgf);     // T1
        accB[i][j][r] = yt;
        nTm2[i][j][r] = -dgf;                                 // -T0
        float base = ACCUM ? L[i][j][r] : 0.f;
        L[i][j][r] = fmaf(c1, yt, fmaf(c0, dgf, base));
      }
  __syncthreads();                                            // Vb reads done before overwrite
  // stage A = 2*Ytilde split -> H/Lo ; stage B = T1 single -> Bu
#pragma unroll
  for (int i = 0; i < 2; ++i)
#pragma unroll
    for (int j = 0; j < 2; ++j) {
      f32x4 y2;
#pragma unroll
      for (int r = 0; r < 4; ++r) y2[r] = accB[i][j][r] + accB[i][j][r];
      stg_split(H, Lo, 16 * j + c15, 16 * i + 4 * g, y2);
      stg_single(Bu, 16 * j + c15, 16 * i + 4 * g, accB[i][j]);
    }
  __syncthreads();
  short8 Ya_h[2], Ya_l[2];
#pragma unroll
  for (int t = 0; t < 2; ++t) {
    Ya_h[t] = fragr(H, t, c15, g);
    Ya_l[t] = fragr(Lo, t, c15, g);
  }
  // 4. forward pairs: T_k = MFMA(2*Ytilde, bf16(T_{k-1}), -T_{k-2}); L += c_k T_k
  f32x4 accA[2][2];
#pragma unroll
  for (int kk = 2; kk < NCHEB; kk += 2) {
    const float cka = cof[kk];
#pragma unroll
    for (int j = 0; j < 2; ++j) {
      short8 B0 = fragr(Bu, j, c15, g);
#pragma unroll
      for (int i = 0; i < 2; ++i) {
        f32x4 a = nTm2[i][j];
        a = MFMA16(Ya_l[i], B0, a);
        a = MFMA16(Ya_h[i], B0, a);
        accA[i][j] = a;
      }
    }
#pragma unroll
    for (int i = 0; i < 2; ++i)
#pragma unroll
      for (int j = 0; j < 2; ++j) {
#pragma unroll
        for (int r = 0; r < 4; ++r) {
          L[i][j][r]    = fmaf(cka, accA[i][j][r], L[i][j][r]);
          nTm2[i][j][r] = -accB[i][j][r];
        }
        stg_single(H, 16 * j + c15, 16 * i + 4 * g, accA[i][j]);
      }
    __syncthreads();
    const float ckb = cof[kk + 1];
#pragma unroll
    for (int j = 0; j < 2; ++j) {
      short8 B1 = fragr(H, j, c15, g);
#pragma unroll
      for (int i = 0; i < 2; ++i) {
        f32x4 a = nTm2[i][j];
        a = MFMA16(Ya_l[i], B1, a);
        a = MFMA16(Ya_h[i], B1, a);
        accB[i][j] = a;
      }
    }
#pragma unroll
    for (int i = 0; i < 2; ++i)
#pragma unroll
      for (int j = 0; j < 2; ++j)
#pragma unroll
        for (int r = 0; r < 4; ++r)
          L[i][j][r] = fmaf(ckb, accB[i][j][r], L[i][j][r]);
    if (kk + 2 < NCHEB) {
#pragma unroll
      for (int i = 0; i < 2; ++i)
#pragma unroll
        for (int j = 0; j < 2; ++j) {
#pragma unroll
          for (int r = 0; r < 4; ++r) nTm2[i][j][r] = -accA[i][j][r];
          stg_single(Bu, 16 * j + c15, 16 * i + 4 * g, accB[i][j]);
        }
      __syncthreads();
    }
  }
  __syncthreads();   // guard: all reads done before next matrix restages H/Lo/Bu
}

// ---------- tiny-kernel helpers (single block, 64 threads; unchanged) ----------

__device__ __forceinline__ float dotrow36(const float* Arow, const float* v) {
  float s = 0.f;
#pragma unroll
  for (int j = 0; j < 8; ++j) {
    float4 a = *reinterpret_cast<const float4*>(Arow + 4 * j);
    s = fmaf(a.x, v[4 * j + 0], s);
    s = fmaf(a.y, v[4 * j + 1], s);
    s = fmaf(a.z, v[4 * j + 2], s);
    s = fmaf(a.w, v[4 * j + 3], s);
  }
  return s;
}

__device__ void mm64(float (*D)[LDSW], const float (*A)[LDSW], const float (*Bm)[LDSW], int lane) {
  const int h = lane >> 5, c = lane & 31;
  float bcol[32];
#pragma unroll
  for (int k = 0; k < 32; ++k) bcol[k] = Bm[k][c];
  float o[16];
#pragma unroll
  for (int i = 0; i < 16; ++i) o[i] = dotrow36(&A[16 * h + i][0], bcol);
  __syncthreads();
#pragma unroll
  for (int i = 0; i < 16; ++i) D[16 * h + i][c] = o[i];
  __syncthreads();
}

__device__ void ns_sqrt(LdsMat& Y, LdsMat& Z, LdsMat& Ya, LdsMat& Za, LdsMat T, int lane) {
  const int h = lane >> 5, c = lane & 31;
  for (int it = 0; it < NS_ITERS; ++it) {
    mm64(T, Z, Y, lane);
#pragma unroll
    for (int i = 0; i < 16; ++i) {
      int r = 16 * h + i;
      T[r][c] = ((r == c) ? 1.5f : 0.f) - 0.5f * T[r][c];
    }
    __syncthreads();
    mm64(Ya, Y, T, lane);
    mm64(Za, T, Z, lane);
    LdsMat t1 = Y; Y = Ya; Ya = t1;
    LdsMat t2 = Z; Z = Za; Za = t2;
  }
}

// ---------- kernels ----------

extern "C" __global__ void __launch_bounds__(256)
spdbn_kA(const float* __restrict__ x, float* __restrict__ wsf) {
  const int e  = (blockIdx.x & 3) * 256 + threadIdx.x;
  const int bs = blockIdx.x >> 2;
  float acc = 0.f;
  for (int t = 0; t < 64; ++t)
    acc += x[(size_t)(bs + 1024 * t) * 1024 + e];
  atomicAdd(&wsf[OFF_MEAN0 + e], acc);
}

extern "C" __global__ void __launch_bounds__(64)
spdbn_kS1(float* __restrict__ wsf) {
  __shared__ alignas(16) float W0[32][LDSW], W1[32][LDSW], W2[32][LDSW], W3[32][LDSW], W4[32][LDSW];
  const int lane = threadIdx.x, h = lane >> 5, c = lane & 31;
  float sacc = 0.f;
#pragma unroll
  for (int k = 0; k < 32; ++k) sacc += wsf[OFF_MEAN0 + 33 * k];
  const float cN = sacc / (32.f * (float)BATCH);
  const float scaleA = 32.f / sacc;
#pragma unroll
  for (int i = 0; i < 16; ++i) {
    int r = 16 * h + i;
    W1[r][c] = wsf[OFF_MEAN0 + r * 32 + c] * scaleA;
    W2[r][c] = (r == c) ? 1.f : 0.f;
  }
  __syncthreads();
  LdsMat Y = W1, Z = W2, Ya = W0, Za = W4;
  ns_sqrt(Y, Z, Ya, Za, W3, lane);
  const float sq = sqrtf(cN), rs = rsqrtf(cN);
#pragma unroll
  for (int i = 0; i < 16; ++i) {
    int r = 16 * h + i;
    wsf[OFF_INVS0 + r * 32 + c] = Z[r][c] * rs;
    wsf[OFF_S0    + r * 32 + c] = Y[r][c] * sq;
  }
  const float PIF = 3.14159265358979f;
  const float th = ((float)lane + 0.5f) * (PIF / 64.f);
  const float t  = 0.5f * (CALPHA + CBETA) + 0.5f * (CBETA - CALPHA) * cosf(th);
  const float fl = logf(t);
  for (int j = 0; j < NCHEB; ++j) {
    float v = fl * cosf((float)j * th) * (2.f / 64.f);
#pragma unroll
    for (int off = 32; off >= 1; off >>= 1) v += __shfl_xor(v, off);
    if (lane == 0) wsf[OFF_CHEB + j] = (j == 0) ? 0.5f * v : v;
  }
}

// Karcher step: accumulate sum_b log(inv_s0 x_b inv_s0)
extern "C" __global__ void __launch_bounds__(64, 3)
spdbn_kB(const float* __restrict__ x, float* __restrict__ wsf) {
  __shared__ alignas(16) u16t H[32][40], Lo[32][40], Bu[32][40];
  const int lane = threadIdx.x;
  const int g = lane >> 4, c15 = lane & 15;
  short8 S_h[2], S_l[2];
  load_sym_frags(wsf + OFF_INVS0, c15, g, S_h, S_l);
  const float* cof = wsf + OFF_CHEB;
  f32x4 dg4;
#pragma unroll
  for (int r = 0; r < 4; ++r) dg4[r] = (4 * g + r == c15) ? 1.f : 0.f;
  f32x4 L[2][2];
#pragma unroll
  for (int i = 0; i < 2; ++i)
#pragma unroll
    for (int j = 0; j < 2; ++j) L[i][j] = (f32x4){0.f, 0.f, 0.f, 0.f};
  const int off0 = c15 * 32 + 8 * g, off1 = (16 + c15) * 32 + 8 * g;
  float4 r0, r1, r2, r3;
  {
    const float* xp = x + (size_t)blockIdx.x * 1024;
    r0 = *reinterpret_cast<const float4*>(xp + off0);
    r1 = *reinterpret_cast<const float4*>(xp + off0 + 4);
    r2 = *reinterpret_cast<const float4*>(xp + off1);
    r3 = *reinterpret_cast<const float4*>(xp + off1 + 4);
  }
  for (int b = blockIdx.x; b < BATCH; b += GRID_B) {
    short8 Xa_h[2], Xa_l[2];
    split8regs(r0, r1, 1.f, Xa_h[0], Xa_l[0]);
    split8regs(r2, r3, 1.f, Xa_h[1], Xa_l[1]);
    int bn = b + GRID_B;
    if (bn < BATCH) {                     // prefetch next matrix (hidden under recurrence)
      const float* xp = x + (size_t)bn * 1024;
      r0 = *reinterpret_cast<const float4*>(xp + off0);
      r1 = *reinterpret_cast<const float4*>(xp + off0 + 4);
      r2 = *reinterpret_cast<const float4*>(xp + off1);
      r3 = *reinterpret_cast<const float4*>(xp + off1 + 4);
    }
    whiten_cheb<true>(Xa_h, Xa_l, S_h, S_l, H, Lo, Bu, cof, g, c15, dg4, L);
  }
#pragma unroll
  for (int i = 0; i < 2; ++i)
#pragma unroll
    for (int j = 0; j < 2; ++j)
#pragma unroll
      for (int r = 0; r < 4; ++r)
        atomicAdd(&wsf[OFF_LOGAVG + (16 * i + 4 * g + r) * 32 + 16 * j + c15], L[i][j][r]);
}

extern "C" __global__ void __launch_bounds__(64)
spdbn_kS2(float* __restrict__ wsf, const float* __restrict__ shift) {
  __shared__ alignas(16) float W0[32][LDSW], W1[32][LDSW], W2[32][LDSW], W3[32][LDSW], W4[32][LDSW];
  const int lane = threadIdx.x, h = lane >> 5, c = lane & 31;
#pragma unroll
  for (int i = 0; i < 16; ++i) {
    int r = 16 * h + i;
    W0[r][c] = wsf[OFF_LOGAVG + r * 32 + c] * (1.f / (float)BATCH);
    W1[r][c] = (r == c) ? 1.f : 0.f;
  }
  __syncthreads();
  for (int j = 12; j >= 1; --j) {          // mean-exp stays at 12 terms (exactness, one-off cost)
    mm64(W3, W0, W1, lane);
    const float inv = 1.f / (float)j;
#pragma unroll
    for (int i = 0; i < 16; ++i) {
      int r = 16 * h + i;
      W1[r][c] = ((r == c) ? 1.f : 0.f) + W3[r][c] * inv;
    }
    __syncthreads();
  }
#pragma unroll
  for (int i = 0; i < 16; ++i) { int r = 16 * h + i; W2[r][c] = wsf[OFF_S0 + r * 32 + c]; }
  __syncthreads();
  mm64(W3, W2, W1, lane);
  mm64(W0, W3, W2, lane);
  float tr = 0.f;
#pragma unroll
  for (int k = 0; k < 32; ++k) tr += W0[k][k];
  tr *= (1.f / 32.f);
  const float itr = 1.f / tr;
#pragma unroll
  for (int i = 0; i < 16; ++i) {
    int r = 16 * h + i;
    W1[r][c] = W0[r][c] * itr;
    W2[r][c] = (r == c) ? 1.f : 0.f;
  }
  __syncthreads();
  LdsMat Y = W1, Z = W2, Ya = W0, Za = W4;
  ns_sqrt(Y, Z, Ya, Za, W3, lane);
  const float rs = rsqrtf(tr);
#pragma unroll
  for (int i = 0; i < 16; ++i) { int r = 16 * h + i; wsf[OFF_INVS + r * 32 + c] = Z[r][c] * rs; }
  __syncthreads();
  float tr2 = 0.f;
#pragma unroll
  for (int k = 0; k < 32; ++k) tr2 += shift[33 * k];
  tr2 *= (1.f / 32.f);
  const float itr2 = 1.f / tr2;
#pragma unroll
  for (int i = 0; i < 16; ++i) {
    int r = 16 * h + i;
    W1[r][c] = shift[r * 32 + c] * itr2;
    W2[r][c] = (r == c) ? 1.f : 0.f;
  }
  __syncthreads();
  LdsMat Y2 = W1, Z2 = W2, Ya2 = W0, Za2 = W4;
  ns_sqrt(Y2, Z2, Ya2, Za2, W3, lane);
  const float sq2 = sqrtf(tr2);
#pragma unroll
  for (int i = 0; i < 16; ++i) { int r = 16 * h + i; wsf[OFF_SSQRT + r * 32 + c] = Y2[r][c] * sq2; }
}

// BN whiten: L_b = log(inv_s x_b inv_s) -> d_out (scratch); var += ||L_b||_F^2
extern "C" __global__ void __launch_bounds__(64, 3)
spdbn_kC(const float* __restrict__ x, float* __restrict__ wsf, float* __restrict__ outL) {
  __shared__ alignas(16) u16t H[32][40], Lo[32][40], Bu[32][40];
  const int lane = threadIdx.x;
  const int g = lane >> 4, c15 = lane & 15;
  short8 S_h[2], S_l[2];
  load_sym_frags(wsf + OFF_INVS, c15, g, S_h, S_l);
  const float* cof = wsf + OFF_CHEB;
  f32x4 dg4;
#pragma unroll
  for (int r = 0; r < 4; ++r) dg4[r] = (4 * g + r == c15) ? 1.f : 0.f;
  float ss = 0.f;
  f32x4 L[2][2];
  const int off0 = c15 * 32 + 8 * g, off1 = (16 + c15) * 32 + 8 * g;
  float4 r0, r1, r2, r3;
  {
    const float* xp = x + (size_t)blockIdx.x * 1024;
    r0 = *reinterpret_cast<const float4*>(xp + off0);
    r1 = *reinterpret_cast<const float4*>(xp + off0 + 4);
    r2 = *reinterpret_cast<const float4*>(xp + off1);
    r3 = *reinterpret_cast<const float4*>(xp + off1 + 4);
  }
  for (int b = blockIdx.x; b < BATCH; b += GRID_C) {
    short8 Xa_h[2], Xa_l[2];
    split8regs(r0, r1, 1.f, Xa_h[0], Xa_l[0]);
    split8regs(r2, r3, 1.f, Xa_h[1], Xa_l[1]);
    int bn = b + GRID_C;
    if (bn < BATCH) {
      const float* xp = x + (size_t)bn * 1024;
      r0 = *reinterpret_cast<const float4*>(xp + off0);
      r1 = *reinterpret_cast<const float4*>(xp + off0 + 4);
      r2 = *reinterpret_cast<const float4*>(xp + off1);
      r3 = *reinterpret_cast<const float4*>(xp + off1 + 4);
    }
    whiten_cheb<false>(Xa_h, Xa_l, S_h, S_l, H, Lo, Bu, cof, g, c15, dg4, L);
    float* ob = outL + (size_t)b * 1024;
#pragma unroll
    for (int i = 0; i < 2; ++i)
#pragma unroll
      for (int j = 0; j < 2; ++j)
#pragma unroll
        for (int r = 0; r < 4; ++r) {
          float v = L[i][j][r];
          ob[(16 * i + 4 * g + r) * 32 + 16 * j + c15] = v;
          ss = fmaf(v, v, ss);
        }
  }
#pragma unroll
  for (int off = 32; off >= 1; off >>= 1) ss += __shfl_xor(ss, off);
  if (lane == 0) atomicAdd(&wsf[OFF_VAR], ss);
}

extern "C" __global__ void spdbn_kS3(float* __restrict__ wsf, const float* __restrict__ scale) {
  if (threadIdx.x == 0) {
    float var = wsf[OFF_VAR] * (1.f / (float)BATCH);
    float stdv = sqrtf(var);
    wsf[OFF_P] = scale[0] / (stdv + 1e-5f);
  }
}

// out = s_sqrt * exp(p*L) * s_sqrt  (reads L from d_out, overwrites in place)
extern "C" __global__ void __launch_bounds__(64, 3)
spdbn_kD(float* __restrict__ out, const float* __restrict__ wsf) {
  __shared__ alignas(16) u16t H[32][40], Lo[32][40], Bu[32][40];
  const int lane = threadIdx.x;
  const int g = lane >> 4, c15 = lane & 15;
  short8 Q_h[2], Q_l[2];
  load_sym_frags(wsf + OFF_SSQRT, c15, g, Q_h, Q_l);
  const float p = wsf[OFF_P];
  const f32x4 z4 = {0.f, 0.f, 0.f, 0.f};
  f32x4 dg4;
#pragma unroll
  for (int r = 0; r < 4; ++r) dg4[r] = (4 * g + r == c15) ? 1.f : 0.f;
  const int off0 = c15 * 32 + 8 * g, off1 = (16 + c15) * 32 + 8 * g;
  float4 r0, r1, r2, r3;
  {
    const float* lp = out + (size_t)blockIdx.x * 1024;
    r0 = *reinterpret_cast<const float4*>(lp + off0);
    r1 = *reinterpret_cast<const float4*>(lp + off0 + 4);
    r2 = *reinterpret_cast<const float4*>(lp + off1);
    r3 = *reinterpret_cast<const float4*>(lp + off1 + 4);
  }
  for (int b = blockIdx.x; b < BATCH; b += GRID_D) {
    float* ob = out + (size_t)b * 1024;
    short8 M_h[2], M_l[2];
    split8regs(r0, r1, p, M_h[0], M_l[0]);
    split8regs(r2, r3, p, M_h[1], M_l[1]);
    int bn = b + GRID_D;
    if (bn < BATCH) {                    // prefetch next L (own stride slice; no hazard)
      const float* lp = out + (size_t)bn * 1024;
      r0 = *reinterpret_cast<const float4*>(lp + off0);
      r1 = *reinterpret_cast<const float4*>(lp + off0 + 4);
      r2 = *reinterpret_cast<const float4*>(lp + off1);
      r3 = *reinterpret_cast<const float4*>(lp + off1 + 4);
    }
    // Taylor: P = I; P = I + (M/jj)P  (single-bf16 B, ping-pong H <-> Bu)
    f32x4 Pv[2][2];
#pragma unroll
    for (int i = 0; i < 2; ++i)
#pragma unroll
      for (int j = 0; j < 2; ++j)
#pragma unroll
        for (int r = 0; r < 4; ++r) Pv[i][j][r] = (i == j) ? dg4[r] : 0.f;
    f32x4 acc[2][2];
#pragma unroll
    for (int jj = EXP_TERMS; jj >= 1; --jj) {
      const int t = EXP_TERMS - jj;
      u16t (*W)[40] = (t & 1) ? Bu : H;
#pragma unroll
      for (int i = 0; i < 2; ++i)
#pragma unroll
        for (int j = 0; j < 2; ++j)
          stg_single(W, 16 * j + c15, 16 * i + 4 * g, Pv[i][j]);
      __syncthreads();
      short8 B0 = fragr(W, 0, c15, g), B1 = fragr(W, 1, c15, g);
#pragma unroll
      for (int i = 0; i < 2; ++i) {
        f32x4 a = z4;
        a = MFMA16(M_l[i], B0, a);
        a = MFMA16(M_h[i], B0, a);
        acc[i][0] = a;
        f32x4 c = z4;
        c = MFMA16(M_l[i], B1, c);
        c = MFMA16(M_h[i], B1, c);
        acc[i][1] = c;
      }
      const float inv = 1.f / (float)jj;
#pragma unroll
      for (int i = 0; i < 2; ++i)
#pragma unroll
        for (int j = 0; j < 2; ++j)
#pragma unroll
          for (int r = 0; r < 4; ++r)
            Pv[i][j][r] = fmaf(acc[i][j][r], inv, (i == j) ? dg4[r] : 0.f);
      __syncthreads();
    }
    // W = P * Ssq   (P symmetric -> A-frags from split staging)
#pragma unroll
    for (int i = 0; i < 2; ++i)
#pragma unroll
      for (int j = 0; j < 2; ++j)
        stg_split(H, Lo, 16 * j + c15, 16 * i + 4 * g, Pv[i][j]);
    __syncthreads();
    short8 Ph[2], Pl[2];
#pragma unroll
    for (int t = 0; t < 2; ++t) { Ph[t] = fragr(H, t, c15, g); Pl[t] = fragr(Lo, t, c15, g); }
#pragma unroll
    for (int i = 0; i < 2; ++i)
#pragma unroll
      for (int j = 0; j < 2; ++j) {
        f32x4 a = z4;
        a = MFMA16(Pl[i], Q_h[j], a);
        a = MFMA16(Ph[i], Q_l[j], a);
        a = MFMA16(Ph[i], Q_h[j], a);
        acc[i][j] = a;
      }
    __syncthreads();
#pragma unroll
    for (int i = 0; i < 2; ++i)
#pragma unroll
      for (int j = 0; j < 2; ++j)
        stg_split(H, Lo, 16 * j + c15, 16 * i + 4 * g, acc[i][j]);
    __syncthreads();
    short8 Wh[2], Wl[2];
#pragma unroll
    for (int j = 0; j < 2; ++j) { Wh[j] = fragr(H, j, c15, g); Wl[j] = fragr(Lo, j, c15, g); }
#pragma unroll
    for (int i = 0; i < 2; ++i)
#pragma unroll
      for (int j = 0; j < 2; ++j) {
        f32x4 a = z4;
        a = MFMA16(Q_l[i], Wh[j], a);
        a = MFMA16(Q_h[i], Wl[j], a);
        a = MFMA16(Q_h[i], Wh[j], a);
        acc[i][j] = a;
      }
#pragma unroll
    for (int i = 0; i < 2; ++i)
#pragma unroll
      for (int j = 0; j < 2; ++j)
#pragma unroll
        for (int r = 0; r < 4; ++r)
          ob[(16 * i + 4 * g + r) * 32 + 16 * j + c15] = acc[i][j][r];
    __syncthreads();
  }
}

extern "C" void kernel_launch(void* const* d_in, const int* in_sizes, int n_in,
                              void* d_out, int out_size, void* d_ws, size_t ws_size,
                              hipStream_t stream) {
  const float* x     = (const float*)d_in[0];
  const float* shift = (const float*)d_in[1];
  const float* scale = (const float*)d_in[2];
  float* out = (float*)d_out;
  float* wsf = (float*)d_ws;

  size_t zbytes = 32768;
  if (ws_size < zbytes) zbytes = ws_size;
  hipMemsetAsync(d_ws, 0, zbytes, stream);

  hipLaunchKernelGGL(spdbn_kA,  dim3(4096),   dim3(256), 0, stream, x, wsf);
  hipLaunchKernelGGL(spdbn_kS1, dim3(1),      dim3(64),  0, stream, wsf);
  hipLaunchKernelGGL(spdbn_kB,  dim3(GRID_B), dim3(64),  0, stream, x, wsf);
  hipLaunchKernelGGL(spdbn_kS2, dim3(1),      dim3(64),  0, stream, wsf, shift);
  hipLaunchKernelGGL(spdbn_kC,  dim3(GRID_C), dim3(64),  0, stream, x, wsf, out);
  hipLaunchKernelGGL(spdbn_kS3, dim3(1),      dim3(64),  0, stream, wsf, scale);
  hipLaunchKernelGGL(spdbn_kD,  dim3(GRID_D), dim3(64),  0, stream, out, wsf);
}

// Round 8
// 1042.920 us; speedup vs baseline: 1.8935x; 1.8935x over previous
//
#include <hip/hip_runtime.h>
#include <cstdint>
#include <cstddef>

#define BATCH       65536
#define LDSW        36          // padded LDS row stride for tiny-kernel matrices
#define NCHEB       16          // Chebyshev terms on [CALPHA, CBETA] (validated r7: absmax unchanged)
#define CALPHA      0.28f       // lambda_min(x) >= 0.5 by construction; whitened >= ~0.33
#define CBETA       4.6f        // MP+TW bound ~5.5 / Karcher-mean ~1.21 => <= ~4.55
#define NS_ITERS    6           // Newton-Schulz sqrt iterations
#define EXP_TERMS   8           // Taylor terms for matrix exp (||pL|| <= ~0.8, tail ~4e-7)
#define MAIN_BLOCKS 3072        // main kernels: 3072 1-wave blocks (12/CU co-resident)

// ws float offsets
#define OFF_MEAN0   0
#define OFF_INVS0   1024
#define OFF_S0      2048
#define OFF_LOGAVG  3072
#define OFF_INVS    4096
#define OFF_SSQRT   5120
#define OFF_VAR     6144
#define OFF_P       6145
#define OFF_CHEB    6152        // NCHEB floats

typedef float (*LdsMat)[LDSW];
typedef __attribute__((ext_vector_type(8))) short short8;
typedef __attribute__((ext_vector_type(4))) float f32x4;
typedef unsigned short u16t;
typedef unsigned int   u32t;

#define MFMA16(a, b, c) __builtin_amdgcn_mfma_f32_16x16x32_bf16((a), (b), (c), 0, 0, 0)

// ---------------- bf16 pack / split helpers (perm-based, 3 ops/dword) ----------------
// pack2_rn: [bf16_rn(b) | bf16_rn(a)] in one dword (round-to-nearest, ties-away)
__device__ __forceinline__ u32t pack2_rn(float a, float b) {
  u32t ua = __float_as_uint(a) + 0x8000u;
  u32t ub = __float_as_uint(b) + 0x8000u;
  return __builtin_amdgcn_perm(ub, ua, 0x07060302u);
}
// split2: hi = rn-bf16 pair (dword), lo = truncated-bf16 pair of the residual
__device__ __forceinline__ void split2(float a, float b, u32t& hw, u32t& lw) {
  u32t ua = __float_as_uint(a) + 0x8000u;
  u32t ub = __float_as_uint(b) + 0x8000u;
  hw = __builtin_amdgcn_perm(ub, ua, 0x07060302u);
  float ra = a - __uint_as_float(ua & 0xFFFF0000u);
  float rb = b - __uint_as_float(ub & 0xFFFF0000u);
  lw = __builtin_amdgcn_perm(__float_as_uint(rb), __float_as_uint(ra), 0x07060302u);
}

// Fragment read from col-major-staged [32][40] u16 array: row 16t+c15, k0 = 8g
__device__ __forceinline__ short8 fragr(const u16t (*G)[40], int t, int c15, int g) {
  return *reinterpret_cast<const short8*>(&G[16 * t + c15][8 * g]);
}
// Stage C-layout tile (4 f32, rows 16i+4g..+3, col 16j+c15): col = 16j+c15, row = 16i+4g
__device__ __forceinline__ void stg_single(u16t (*G)[40], int col, int row, f32x4 v) {
  uint2 w; w.x = pack2_rn(v[0], v[1]); w.y = pack2_rn(v[2], v[3]);
  *reinterpret_cast<uint2*>(&G[col][row]) = w;
}
__device__ __forceinline__ void stg_split(u16t (*Gh)[40], u16t (*Gl)[40], int col, int row, f32x4 v) {
  u32t h0, l0, h1, l1;
  split2(v[0], v[1], h0, l0);
  split2(v[2], v[3], h1, l1);
  uint2 hv; hv.x = h0; hv.y = h1;
  uint2 lv; lv.x = l0; lv.y = l1;
  *reinterpret_cast<uint2*>(&Gh[col][row]) = hv;
  *reinterpret_cast<uint2*>(&Gl[col][row]) = lv;
}

// legacy scalar split (used only in once-per-kernel frag loads)
__device__ __forceinline__ void splitf(float a, u16t& h, u16t& l) {
  unsigned u  = __float_as_uint(a);
  unsigned uh = (u + 0x8000u) & 0xFFFF0000u;
  float    r  = a - __uint_as_float(uh);
  unsigned ul = __float_as_uint(r) + 0x8000u;
  h = (u16t)(uh >> 16);
  l = (u16t)(ul >> 16);
}

// Load hi/lo fragments of a symmetric 32x32 f32 matrix from global (ws).
__device__ __forceinline__ void load_sym_frags(const float* base, int c15, int g,
                                               short8* Fh, short8* Fl) {
#pragma unroll
  for (int t = 0; t < 2; ++t) {
    const float* sp = base + (16 * t + c15) * 32 + 8 * g;
    short8 hh, ll;
#pragma unroll
    for (int j = 0; j < 8; ++j) {
      u16t h, l;
      splitf(sp[j], h, l);
      hh[j] = (short)h;
      ll[j] = (short)l;
    }
    Fh[t] = hh;
    Fl[t] = ll;
  }
}

// ---------------- MFMA whiten + forward-Chebyshev log core (round-4 code, verbatim) ----------------
// L = cheb_log( GSC*(S x S) - MSH*I ).  A-side (2*Ytilde) kept split hi/lo; the
// recurrence B-operand (T_{k-1}) is single rn-bf16; -T_{k-2} folded into MFMA C.
template <bool ACCUM>
__device__ __forceinline__ void whiten_cheb(
    const float* __restrict__ xb, const short8* S_h, const short8* S_l,
    u16t (*Xh)[40], u16t (*Xl)[40], u16t (*Bu0)[40], u16t (*Bu1)[40],
    const float* cof, int g, int c15, const f32x4& dg4, f32x4 (&L)[2][2]) {
  const f32x4 z4 = {0.f, 0.f, 0.f, 0.f};
  const int lane = 16 * g + c15;
  // 1. stage X split into Xh/Xl
#pragma unroll
  for (int e = 0; e < 4; ++e) {
    int idx = e * 256 + lane * 4;
    float4 v = *reinterpret_cast<const float4*>(xb + idx);
    int row = idx >> 5, col = idx & 31;
    u32t h0, l0, h1, l1;
    split2(v.x, v.y, h0, l0);
    split2(v.z, v.w, h1, l1);
    uint2 hv; hv.x = h0; hv.y = h1;
    uint2 lv; lv.x = l0; lv.y = l1;
    *reinterpret_cast<uint2*>(&Xh[row][col]) = hv;
    *reinterpret_cast<uint2*>(&Xl[row][col]) = lv;
  }
  __syncthreads();
  f32x4 acc[2][2];
  // 2. V2 = X * S  (split x split, 3 MFMA/tile) -> stage split into Bu0/Bu1
#pragma unroll
  for (int i = 0; i < 2; ++i) {
    short8 Xa_h = fragr(Xh, i, c15, g), Xa_l = fragr(Xl, i, c15, g);
#pragma unroll
    for (int j = 0; j < 2; ++j) {
      f32x4 a = z4;
      a = MFMA16(Xa_l, S_h[j], a);
      a = MFMA16(Xa_h, S_l[j], a);
      a = MFMA16(Xa_h, S_h[j], a);
      acc[i][j] = a;
    }
  }
  __syncthreads();
#pragma unroll
  for (int i = 0; i < 2; ++i)
#pragma unroll
    for (int j = 0; j < 2; ++j)
      stg_split(Bu0, Bu1, 16 * j + c15, 16 * i + 4 * g, acc[i][j]);
  __syncthreads();
  // 3. Y = S * V2 -> Ytilde
#pragma unroll
  for (int j = 0; j < 2; ++j) {
    short8 Bh = fragr(Bu0, j, c15, g), Bl = fragr(Bu1, j, c15, g);
#pragma unroll
    for (int i = 0; i < 2; ++i) {
      f32x4 a = z4;
      a = MFMA16(S_l[i], Bh, a);
      a = MFMA16(S_h[i], Bl, a);
      a = MFMA16(S_h[i], Bh, a);
      acc[i][j] = a;
    }
  }
  const float GSC = 2.f / (CBETA - CALPHA);
  const float MSH = (CALPHA + CBETA) / (CBETA - CALPHA);
  const float c0 = cof[0], c1 = cof[1];
  f32x4 nTm2[2][2], accB[2][2];
#pragma unroll
  for (int i = 0; i < 2; ++i)
#pragma unroll
    for (int j = 0; j < 2; ++j)
#pragma unroll
      for (int r = 0; r < 4; ++r) {
        float dgf = (i == j) ? dg4[r] : 0.f;
        float yt  = fmaf(acc[i][j][r], GSC, -MSH * dgf);   // Ytilde (= T1)
        accB[i][j][r] = yt;
        nTm2[i][j][r] = -dgf;                              // -T0
        float base = ACCUM ? L[i][j][r] : 0.f;
        L[i][j][r]  = fmaf(c1, yt, fmaf(c0, dgf, base));
      }
  __syncthreads();
  // stage A = 2*Ytilde split -> Xh/Xl (X dead); stage B = T1 single -> Bu0
#pragma unroll
  for (int i = 0; i < 2; ++i)
#pragma unroll
    for (int j = 0; j < 2; ++j) {
      f32x4 y2;
#pragma unroll
      for (int r = 0; r < 4; ++r) y2[r] = accB[i][j][r] + accB[i][j][r];
      stg_split(Xh, Xl, 16 * j + c15, 16 * i + 4 * g, y2);
      stg_single(Bu0, 16 * j + c15, 16 * i + 4 * g, accB[i][j]);
    }
  __syncthreads();
  short8 Yh2[2], Yl2[2];
#pragma unroll
  for (int t = 0; t < 2; ++t) { Yh2[t] = fragr(Xh, t, c15, g); Yl2[t] = fragr(Xl, t, c15, g); }
  // 4. T_k = MFMA(2*Ytilde, T_{k-1}, -T_{k-2});  L += c_k T_k   (pairs, ping-pong)
  f32x4 accA[2][2];
#pragma unroll
  for (int kk = 2; kk < NCHEB; kk += 2) {
    const float cka = cof[kk];
#pragma unroll
    for (int j = 0; j < 2; ++j) {
      short8 Bh = fragr(Bu0, j, c15, g);
#pragma unroll
      for (int i = 0; i < 2; ++i) {
        f32x4 a = nTm2[i][j];
        a = MFMA16(Yl2[i], Bh, a);
        a = MFMA16(Yh2[i], Bh, a);
        accA[i][j] = a;
      }
    }
#pragma unroll
    for (int i = 0; i < 2; ++i)
#pragma unroll
      for (int j = 0; j < 2; ++j)
#pragma unroll
        for (int r = 0; r < 4; ++r) {
          L[i][j][r]    = fmaf(cka, accA[i][j][r], L[i][j][r]);
          nTm2[i][j][r] = -accB[i][j][r];
        }
#pragma unroll
    for (int i = 0; i < 2; ++i)
#pragma unroll
      for (int j = 0; j < 2; ++j)
        stg_single(Bu1, 16 * j + c15, 16 * i + 4 * g, accA[i][j]);
    __syncthreads();
    const float ckb = cof[kk + 1];
#pragma unroll
    for (int j = 0; j < 2; ++j) {
      short8 Bh = fragr(Bu1, j, c15, g);
#pragma unroll
      for (int i = 0; i < 2; ++i) {
        f32x4 a = nTm2[i][j];
        a = MFMA16(Yl2[i], Bh, a);
        a = MFMA16(Yh2[i], Bh, a);
        accB[i][j] = a;
      }
    }
#pragma unroll
    for (int i = 0; i < 2; ++i)
#pragma unroll
      for (int j = 0; j < 2; ++j)
#pragma unroll
        for (int r = 0; r < 4; ++r)
          L[i][j][r] = fmaf(ckb, accB[i][j][r], L[i][j][r]);
    if (kk + 2 < NCHEB) {
#pragma unroll
      for (int i = 0; i < 2; ++i)
#pragma unroll
        for (int j = 0; j < 2; ++j) {
#pragma unroll
          for (int r = 0; r < 4; ++r) nTm2[i][j][r] = -accA[i][j][r];
          stg_single(Bu0, 16 * j + c15, 16 * i + 4 * g, accB[i][j]);
        }
      __syncthreads();
    }
  }
}

// ---------- tiny-kernel helpers (single block, 64 threads; unchanged) ----------

__device__ __forceinline__ float dotrow36(const float* Arow, const float* v) {
  float s = 0.f;
#pragma unroll
  for (int j = 0; j < 8; ++j) {
    float4 a = *reinterpret_cast<const float4*>(Arow + 4 * j);
    s = fmaf(a.x, v[4 * j + 0], s);
    s = fmaf(a.y, v[4 * j + 1], s);
    s = fmaf(a.z, v[4 * j + 2], s);
    s = fmaf(a.w, v[4 * j + 3], s);
  }
  return s;
}

__device__ void mm64(float (*D)[LDSW], const float (*A)[LDSW], const float (*Bm)[LDSW], int lane) {
  const int h = lane >> 5, c = lane & 31;
  float bcol[32];
#pragma unroll
  for (int k = 0; k < 32; ++k) bcol[k] = Bm[k][c];
  float o[16];
#pragma unroll
  for (int i = 0; i < 16; ++i) o[i] = dotrow36(&A[16 * h + i][0], bcol);
  __syncthreads();
#pragma unroll
  for (int i = 0; i < 16; ++i) D[16 * h + i][c] = o[i];
  __syncthreads();
}

__device__ void ns_sqrt(LdsMat& Y, LdsMat& Z, LdsMat& Ya, LdsMat& Za, LdsMat T, int lane) {
  const int h = lane >> 5, c = lane & 31;
  for (int it = 0; it < NS_ITERS; ++it) {
    mm64(T, Z, Y, lane);
#pragma unroll
    for (int i = 0; i < 16; ++i) {
      int r = 16 * h + i;
      T[r][c] = ((r == c) ? 1.5f : 0.f) - 0.5f * T[r][c];
    }
    __syncthreads();
    mm64(Ya, Y, T, lane);
    mm64(Za, T, Z, lane);
    LdsMat t1 = Y; Y = Ya; Ya = t1;
    LdsMat t2 = Z; Z = Za; Za = t2;
  }
}

// ---------- kernels ----------

extern "C" __global__ void __launch_bounds__(256)
spdbn_kA(const float* __restrict__ x, float* __restrict__ wsf) {
  const int e  = (blockIdx.x & 3) * 256 + threadIdx.x;
  const int bs = blockIdx.x >> 2;
  float acc = 0.f;
  for (int t = 0; t < 64; ++t)
    acc += x[(size_t)(bs + 1024 * t) * 1024 + e];
  atomicAdd(&wsf[OFF_MEAN0 + e], acc);
}

extern "C" __global__ void __launch_bounds__(64)
spdbn_kS1(float* __restrict__ wsf) {
  __shared__ alignas(16) float W0[32][LDSW], W1[32][LDSW], W2[32][LDSW], W3[32][LDSW], W4[32][LDSW];
  const int lane = threadIdx.x, h = lane >> 5, c = lane & 31;
  float sacc = 0.f;
#pragma unroll
  for (int k = 0; k < 32; ++k) sacc += wsf[OFF_MEAN0 + 33 * k];
  const float cN = sacc / (32.f * (float)BATCH);
  const float scaleA = 32.f / sacc;
#pragma unroll
  for (int i = 0; i < 16; ++i) {
    int r = 16 * h + i;
    W1[r][c] = wsf[OFF_MEAN0 + r * 32 + c] * scaleA;
    W2[r][c] = (r == c) ? 1.f : 0.f;
  }
  __syncthreads();
  LdsMat Y = W1, Z = W2, Ya = W0, Za = W4;
  ns_sqrt(Y, Z, Ya, Za, W3, lane);
  const float sq = sqrtf(cN), rs = rsqrtf(cN);
#pragma unroll
  for (int i = 0; i < 16; ++i) {
    int r = 16 * h + i;
    wsf[OFF_INVS0 + r * 32 + c] = Z[r][c] * rs;
    wsf[OFF_S0    + r * 32 + c] = Y[r][c] * sq;
  }
  const float PIF = 3.14159265358979f;
  const float th = ((float)lane + 0.5f) * (PIF / 64.f);
  const float t  = 0.5f * (CALPHA + CBETA) + 0.5f * (CBETA - CALPHA) * cosf(th);
  const float fl = logf(t);
  for (int j = 0; j < NCHEB; ++j) {
    float v = fl * cosf((float)j * th) * (2.f / 64.f);
#pragma unroll
    for (int off = 32; off >= 1; off >>= 1) v += __shfl_xor(v, off);
    if (lane == 0) wsf[OFF_CHEB + j] = (j == 0) ? 0.5f * v : v;
  }
}

// Karcher step: accumulate sum_b log(inv_s0 x_b inv_s0)
extern "C" __global__ void __launch_bounds__(64, 3)
spdbn_kB(const float* __restrict__ x, float* __restrict__ wsf) {
  __shared__ alignas(16) u16t Xh[32][40], Xl[32][40], Bu0[32][40], Bu1[32][40];
  const int lane = threadIdx.x;
  const int g = lane >> 4, c15 = lane & 15;
  short8 S_h[2], S_l[2];
  load_sym_frags(wsf + OFF_INVS0, c15, g, S_h, S_l);
  float cof[NCHEB];
#pragma unroll
  for (int k = 0; k < NCHEB; ++k) cof[k] = wsf[OFF_CHEB + k];
  f32x4 dg4;
#pragma unroll
  for (int r = 0; r < 4; ++r) dg4[r] = (4 * g + r == c15) ? 1.f : 0.f;
  f32x4 L[2][2];
#pragma unroll
  for (int i = 0; i < 2; ++i)
#pragma unroll
    for (int j = 0; j < 2; ++j) L[i][j] = (f32x4){0.f, 0.f, 0.f, 0.f};
  for (int b = blockIdx.x; b < BATCH; b += MAIN_BLOCKS) {
    whiten_cheb<true>(x + (size_t)b * 1024, S_h, S_l, Xh, Xl, Bu0, Bu1, cof, g, c15, dg4, L);
    __syncthreads();
  }
#pragma unroll
  for (int i = 0; i < 2; ++i)
#pragma unroll
    for (int j = 0; j < 2; ++j)
#pragma unroll
      for (int r = 0; r < 4; ++r)
        atomicAdd(&wsf[OFF_LOGAVG + (16 * i + 4 * g + r) * 32 + 16 * j + c15], L[i][j][r]);
}

extern "C" __global__ void __launch_bounds__(64)
spdbn_kS2(float* __restrict__ wsf, const float* __restrict__ shift) {
  __shared__ alignas(16) float W0[32][LDSW], W1[32][LDSW], W2[32][LDSW], W3[32][LDSW], W4[32][LDSW];
  const int lane = threadIdx.x, h = lane >> 5, c = lane & 31;
#pragma unroll
  for (int i = 0; i < 16; ++i) {
    int r = 16 * h + i;
    W0[r][c] = wsf[OFF_LOGAVG + r * 32 + c] * (1.f / (float)BATCH);
    W1[r][c] = (r == c) ? 1.f : 0.f;
  }
  __syncthreads();
  for (int j = 12; j >= 1; --j) {          // mean-exp stays at 12 f32 terms (one-off cost)
    mm64(W3, W0, W1, lane);
    const float inv = 1.f / (float)j;
#pragma unroll
    for (int i = 0; i < 16; ++i) {
      int r = 16 * h + i;
      W1[r][c] = ((r == c) ? 1.f : 0.f) + W3[r][c] * inv;
    }
    __syncthreads();
  }
#pragma unroll
  for (int i = 0; i < 16; ++i) { int r = 16 * h + i; W2[r][c] = wsf[OFF_S0 + r * 32 + c]; }
  __syncthreads();
  mm64(W3, W2, W1, lane);
  mm64(W0, W3, W2, lane);
  float tr = 0.f;
#pragma unroll
  for (int k = 0; k < 32; ++k) tr += W0[k][k];
  tr *= (1.f / 32.f);
  const float itr = 1.f / tr;
#pragma unroll
  for (int i = 0; i < 16; ++i) {
    int r = 16 * h + i;
    W1[r][c] = W0[r][c] * itr;
    W2[r][c] = (r == c) ? 1.f : 0.f;
  }
  __syncthreads();
  LdsMat Y = W1, Z = W2, Ya = W0, Za = W4;
  ns_sqrt(Y, Z, Ya, Za, W3, lane);
  const float rs = rsqrtf(tr);
#pragma unroll
  for (int i = 0; i < 16; ++i) { int r = 16 * h + i; wsf[OFF_INVS + r * 32 + c] = Z[r][c] * rs; }
  __syncthreads();
  float tr2 = 0.f;
#pragma unroll
  for (int k = 0; k < 32; ++k) tr2 += shift[33 * k];
  tr2 *= (1.f / 32.f);
  const float itr2 = 1.f / tr2;
#pragma unroll
  for (int i = 0; i < 16; ++i) {
    int r = 16 * h + i;
    W1[r][c] = shift[r * 32 + c] * itr2;
    W2[r][c] = (r == c) ? 1.f : 0.f;
  }
  __syncthreads();
  LdsMat Y2 = W1, Z2 = W2, Ya2 = W0, Za2 = W4;
  ns_sqrt(Y2, Z2, Ya2, Za2, W3, lane);
  const float sq2 = sqrtf(tr2);
#pragma unroll
  for (int i = 0; i < 16; ++i) { int r = 16 * h + i; wsf[OFF_SSQRT + r * 32 + c] = Y2[r][c] * sq2; }
}

// BN whiten: L_b = log(inv_s x_b inv_s) -> d_out (scratch); var += ||L_b||_F^2
extern "C" __global__ void __launch_bounds__(64, 3)
spdbn_kC(const float* __restrict__ x, float* __restrict__ wsf, float* __restrict__ outL) {
  __shared__ alignas(16) u16t Xh[32][40], Xl[32][40], Bu0[32][40], Bu1[32][40];
  const int lane = threadIdx.x;
  const int g = lane >> 4, c15 = lane & 15;
  short8 S_h[2], S_l[2];
  load_sym_frags(wsf + OFF_INVS, c15, g, S_h, S_l);
  float cof[NCHEB];
#pragma unroll
  for (int k = 0; k < NCHEB; ++k) cof[k] = wsf[OFF_CHEB + k];
  f32x4 dg4;
#pragma unroll
  for (int r = 0; r < 4; ++r) dg4[r] = (4 * g + r == c15) ? 1.f : 0.f;
  float ss = 0.f;
  f32x4 L[2][2];
  for (int b = blockIdx.x; b < BATCH; b += MAIN_BLOCKS) {
    whiten_cheb<false>(x + (size_t)b * 1024, S_h, S_l, Xh, Xl, Bu0, Bu1, cof, g, c15, dg4, L);
    float* ob = outL + (size_t)b * 1024;
#pragma unroll
    for (int i = 0; i < 2; ++i)
#pragma unroll
      for (int j = 0; j < 2; ++j)
#pragma unroll
        for (int r = 0; r < 4; ++r) {
          float v = L[i][j][r];
          ob[(16 * i + 4 * g + r) * 32 + 16 * j + c15] = v;
          ss = fmaf(v, v, ss);
        }
    __syncthreads();
  }
#pragma unroll
  for (int off = 32; off >= 1; off >>= 1) ss += __shfl_xor(ss, off);
  if (lane == 0) atomicAdd(&wsf[OFF_VAR], ss);
}

extern "C" __global__ void spdbn_kS3(float* __restrict__ wsf, const float* __restrict__ scale) {
  if (threadIdx.x == 0) {
    float var = wsf[OFF_VAR] * (1.f / (float)BATCH);
    float stdv = sqrtf(var);
    wsf[OFF_P] = scale[0] / (stdv + 1e-5f);
  }
}

// out = s_sqrt * exp(p*L) * s_sqrt  (reads L from d_out, overwrites in place)
extern "C" __global__ void __launch_bounds__(64, 3)
spdbn_kD(float* __restrict__ out, const float* __restrict__ wsf) {
  __shared__ alignas(16) u16t Xh[32][40], Xl[32][40], Bu0[32][40], Bu1[32][40];
  const int lane = threadIdx.x;
  const int g = lane >> 4, c15 = lane & 15;
  short8 Q_h[2], Q_l[2];
  load_sym_frags(wsf + OFF_SSQRT, c15, g, Q_h, Q_l);
  const float p = wsf[OFF_P];
  const f32x4 z4 = {0.f, 0.f, 0.f, 0.f};
  f32x4 dg4;
#pragma unroll
  for (int r = 0; r < 4; ++r) dg4[r] = (4 * g + r == c15) ? 1.f : 0.f;
  // identity tile packed dwords (constant per lane)
  uint2 idp; idp.x = pack2_rn(dg4[0], dg4[1]); idp.y = pack2_rn(dg4[2], dg4[3]);
  uint2 zp;  zp.x = 0u; zp.y = 0u;
  for (int b = blockIdx.x; b < BATCH; b += MAIN_BLOCKS) {
    float* ob = out + (size_t)b * 1024;
    // stage M = p*L split -> Xh/Xl
#pragma unroll
    for (int e = 0; e < 4; ++e) {
      int idx = e * 256 + lane * 4;
      float4 v = *reinterpret_cast<const float4*>(ob + idx);
      int row = idx >> 5, col = idx & 31;
      u32t h0, l0, h1, l1;
      split2(v.x * p, v.y * p, h0, l0);
      split2(v.z * p, v.w * p, h1, l1);
      uint2 hv; hv.x = h0; hv.y = h1;
      uint2 lv; lv.x = l0; lv.y = l1;
      *reinterpret_cast<uint2*>(&Xh[row][col]) = hv;
      *reinterpret_cast<uint2*>(&Xl[row][col]) = lv;
    }
    // P = I staged single-bf16 into Bu0
#pragma unroll
    for (int i = 0; i < 2; ++i)
#pragma unroll
      for (int j = 0; j < 2; ++j)
        *reinterpret_cast<uint2*>(&Bu0[16 * j + c15][16 * i + 4 * g]) = (i == j) ? idp : zp;
    __syncthreads();
    short8 Mh[2], Ml[2];
#pragma unroll
    for (int t = 0; t < 2; ++t) { Mh[t] = fragr(Xh, t, c15, g); Ml[t] = fragr(Xl, t, c15, g); }
    // Taylor: P = I + (M/jj) P, jj = EXP_TERMS..2 (single-bf16 B, split M)
    f32x4 acc[2][2];
#pragma unroll
    for (int jj = EXP_TERMS; jj >= 2; --jj) {
      const int t = EXP_TERMS - jj;
      const u16t (*R)[40] = (t & 1) ? Bu1 : Bu0;
      u16t (*W)[40]       = (t & 1) ? Bu0 : Bu1;
#pragma unroll
      for (int j = 0; j < 2; ++j) {
        short8 Bh = fragr(R, j, c15, g);
#pragma unroll
        for (int i = 0; i < 2; ++i) {
          f32x4 a = z4;
          a = MFMA16(Ml[i], Bh, a);
          a = MFMA16(Mh[i], Bh, a);
          acc[i][j] = a;
        }
      }
      const float inv = 1.f / (float)jj;
      __syncthreads();
#pragma unroll
      for (int i = 0; i < 2; ++i)
#pragma unroll
        for (int j = 0; j < 2; ++j) {
          f32x4 v;
#pragma unroll
          for (int r = 0; r < 4; ++r)
            v[r] = fmaf(acc[i][j][r], inv, ((16 * i + 4 * g + r) == (16 * j + c15)) ? 1.f : 0.f);
          stg_single(W, 16 * j + c15, 16 * i + 4 * g, v);
        }
      __syncthreads();
    }
    // final jj=1 in f32: Pf = I + M*P  (read Bu1: EXP_TERMS even -> last write was Bu1)
#pragma unroll
    for (int j = 0; j < 2; ++j) {
      short8 Bh = fragr(Bu1, j, c15, g);
#pragma unroll
      for (int i = 0; i < 2; ++i) {
        f32x4 a = z4;
        a = MFMA16(Ml[i], Bh, a);
        a = MFMA16(Mh[i], Bh, a);
        acc[i][j] = a;
      }
    }
    __syncthreads();
#pragma unroll
    for (int i = 0; i < 2; ++i)
#pragma unroll
      for (int j = 0; j < 2; ++j) {
        f32x4 v;
#pragma unroll
        for (int r = 0; r < 4; ++r)
          v[r] = acc[i][j][r] + (((16 * i + 4 * g + r) == (16 * j + c15)) ? 1.f : 0.f);
        stg_split(Xh, Xl, 16 * j + c15, 16 * i + 4 * g, v);
      }
    __syncthreads();
    short8 Ph[2], Pl[2];
#pragma unroll
    for (int t = 0; t < 2; ++t) { Ph[t] = fragr(Xh, t, c15, g); Pl[t] = fragr(Xl, t, c15, g); }
    // W = P * Ssq (split x split) -> stage split -> Bu0/Bu1
#pragma unroll
    for (int i = 0; i < 2; ++i)
#pragma unroll
      for (int j = 0; j < 2; ++j) {
        f32x4 a = z4;
        a = MFMA16(Pl[i], Q_h[j], a);
        a = MFMA16(Ph[i], Q_l[j], a);
        a = MFMA16(Ph[i], Q_h[j], a);
        acc[i][j] = a;
      }
    __syncthreads();
#pragma unroll
    for (int i = 0; i < 2; ++i)
#pragma unroll
      for (int j = 0; j < 2; ++j)
        stg_split(Bu0, Bu1, 16 * j + c15, 16 * i + 4 * g, acc[i][j]);
    __syncthreads();
    // out = Ssq * W
#pragma unroll
    for (int j = 0; j < 2; ++j) {
      short8 Wh = fragr(Bu0, j, c15, g), Wl = fragr(Bu1, j, c15, g);
#pragma unroll
      for (int i = 0; i < 2; ++i) {
        f32x4 a = z4;
        a = MFMA16(Q_l[i], Wh, a);
        a = MFMA16(Q_h[i], Wl, a);
        a = MFMA16(Q_h[i], Wh, a);
        acc[i][j] = a;
      }
    }
#pragma unroll
    for (int i = 0; i < 2; ++i)
#pragma unroll
      for (int j = 0; j < 2; ++j)
#pragma unroll
        for (int r = 0; r < 4; ++r)
          ob[(16 * i + 4 * g + r) * 32 + 16 * j + c15] = acc[i][j][r];
    __syncthreads();
  }
}

extern "C" void kernel_launch(void* const* d_in, const int* in_sizes, int n_in,
                              void* d_out, int out_size, void* d_ws, size_t ws_size,
                              hipStream_t stream) {
  const float* x     = (const float*)d_in[0];
  const float* shift = (const float*)d_in[1];
  const float* scale = (const float*)d_in[2];
  float* out = (float*)d_out;
  float* wsf = (float*)d_ws;

  size_t zbytes = 32768;
  if (ws_size < zbytes) zbytes = ws_size;
  hipMemsetAsync(d_ws, 0, zbytes, stream);

  hipLaunchKernelGGL(spdbn_kA,  dim3(4096), dim3(256), 0, stream, x, wsf);
  hipLaunchKernelGGL(spdbn_kS1, dim3(1),    dim3(64),  0, stream, wsf);
  hipLaunchKernelGGL(spdbn_kB,  dim3(MAIN_BLOCKS), dim3(64), 0, stream, x, wsf);
  hipLaunchKernelGGL(spdbn_kS2, dim3(1),    dim3(64),  0, stream, wsf, shift);
  hipLaunchKernelGGL(spdbn_kC,  dim3(MAIN_BLOCKS), dim3(64), 0, stream, x, wsf, out);
  hipLaunchKernelGGL(spdbn_kS3, dim3(1),    dim3(64),  0, stream, wsf, scale);
  hipLaunchKernelGGL(spdbn_kD,  dim3(MAIN_BLOCKS), dim3(64), 0, stream, out, wsf);
}

// Round 9
// 700.188 us; speedup vs baseline: 2.8204x; 1.4895x over previous
//
#include <hip/hip_runtime.h>
#include <cstdint>
#include <cstddef>

#define BATCH       65536
#define LDSW        36          // padded LDS row stride for tiny-kernel matrices
#define NCHEB       16          // Chebyshev terms on [CALPHA, CBETA] (validated r7/r8)
#define CALPHA      0.28f       // lambda_min(x) >= 0.5 by construction; whitened >= ~0.33
#define CBETA       4.6f        // MP+TW bound ~5.5 / Karcher-mean ~1.21 => <= ~4.55
#define NS_ITERS    4           // Newton-Schulz iters (inputs 1 +/- <=0.02 -> <=1e-8)
#define EXP_TERMS   8           // Taylor terms for matrix exp (||pL|| <= ~0.8, tail ~4e-7)
#define MAIN_BLOCKS 3072        // main kernels: 3072 1-wave blocks (12/CU co-resident)

// ws float offsets
#define OFF_MEAN0   0
#define OFF_INVS0   1024
#define OFF_S0      2048
#define OFF_LOGAVG  3072
#define OFF_INVS    4096
#define OFF_SSQRT   5120
#define OFF_VAR     6144
#define OFF_P       6145
#define OFF_CHEB    6152        // NCHEB floats

typedef float (*LdsMat)[LDSW];
typedef __attribute__((ext_vector_type(8))) short short8;
typedef __attribute__((ext_vector_type(4))) float f32x4;
typedef unsigned short u16t;
typedef unsigned int   u32t;

#define MFMA16(a, b, c) __builtin_amdgcn_mfma_f32_16x16x32_bf16((a), (b), (c), 0, 0, 0)

// ---------------- bf16 pack / split helpers (perm-based, 3 ops/dword) ----------------
__device__ __forceinline__ u32t pack2_rn(float a, float b) {
  u32t ua = __float_as_uint(a) + 0x8000u;
  u32t ub = __float_as_uint(b) + 0x8000u;
  return __builtin_amdgcn_perm(ub, ua, 0x07060302u);
}
__device__ __forceinline__ void split2(float a, float b, u32t& hw, u32t& lw) {
  u32t ua = __float_as_uint(a) + 0x8000u;
  u32t ub = __float_as_uint(b) + 0x8000u;
  hw = __builtin_amdgcn_perm(ub, ua, 0x07060302u);
  float ra = a - __uint_as_float(ua & 0xFFFF0000u);
  float rb = b - __uint_as_float(ub & 0xFFFF0000u);
  lw = __builtin_amdgcn_perm(__float_as_uint(rb), __float_as_uint(ra), 0x07060302u);
}

// Fragment read from col-major-staged [32][40] u16 array: row 16t+c15, k0 = 8g
__device__ __forceinline__ short8 fragr(const u16t (*G)[40], int t, int c15, int g) {
  return *reinterpret_cast<const short8*>(&G[16 * t + c15][8 * g]);
}
__device__ __forceinline__ void stg_single(u16t (*G)[40], int col, int row, f32x4 v) {
  uint2 w; w.x = pack2_rn(v[0], v[1]); w.y = pack2_rn(v[2], v[3]);
  *reinterpret_cast<uint2*>(&G[col][row]) = w;
}
__device__ __forceinline__ void stg_split(u16t (*Gh)[40], u16t (*Gl)[40], int col, int row, f32x4 v) {
  u32t h0, l0, h1, l1;
  split2(v[0], v[1], h0, l0);
  split2(v[2], v[3], h1, l1);
  uint2 hv; hv.x = h0; hv.y = h1;
  uint2 lv; lv.x = l0; lv.y = l1;
  *reinterpret_cast<uint2*>(&Gh[col][row]) = hv;
  *reinterpret_cast<uint2*>(&Gl[col][row]) = lv;
}

// legacy scalar split (used only in once-per-kernel frag loads)
__device__ __forceinline__ void splitf(float a, u16t& h, u16t& l) {
  unsigned u  = __float_as_uint(a);
  unsigned uh = (u + 0x8000u) & 0xFFFF0000u;
  float    r  = a - __uint_as_float(uh);
  unsigned ul = __float_as_uint(r) + 0x8000u;
  h = (u16t)(uh >> 16);
  l = (u16t)(ul >> 16);
}

// Load hi/lo fragments of a symmetric 32x32 f32 matrix from global (ws).
__device__ __forceinline__ void load_sym_frags(const float* base, int c15, int g,
                                               short8* Fh, short8* Fl) {
#pragma unroll
  for (int t = 0; t < 2; ++t) {
    const float* sp = base + (16 * t + c15) * 32 + 8 * g;
    short8 hh, ll;
#pragma unroll
    for (int j = 0; j < 8; ++j) {
      u16t h, l;
      splitf(sp[j], h, l);
      hh[j] = (short)h;
      ll[j] = (short)l;
    }
    Fh[t] = hh;
    Fl[t] = ll;
  }
}

// ---------------- MFMA whiten + forward-Chebyshev log core (round-4 code, verbatim) ----------------
template <bool ACCUM>
__device__ __forceinline__ void whiten_cheb(
    const float* __restrict__ xb, const short8* S_h, const short8* S_l,
    u16t (*Xh)[40], u16t (*Xl)[40], u16t (*Bu0)[40], u16t (*Bu1)[40],
    const float* cof, int g, int c15, const f32x4& dg4, f32x4 (&L)[2][2]) {
  const f32x4 z4 = {0.f, 0.f, 0.f, 0.f};
  const int lane = 16 * g + c15;
  // 1. stage X split into Xh/Xl
#pragma unroll
  for (int e = 0; e < 4; ++e) {
    int idx = e * 256 + lane * 4;
    float4 v = *reinterpret_cast<const float4*>(xb + idx);
    int row = idx >> 5, col = idx & 31;
    u32t h0, l0, h1, l1;
    split2(v.x, v.y, h0, l0);
    split2(v.z, v.w, h1, l1);
    uint2 hv; hv.x = h0; hv.y = h1;
    uint2 lv; lv.x = l0; lv.y = l1;
    *reinterpret_cast<uint2*>(&Xh[row][col]) = hv;
    *reinterpret_cast<uint2*>(&Xl[row][col]) = lv;
  }
  __syncthreads();
  f32x4 acc[2][2];
  // 2. V2 = X * S  (split x split, 3 MFMA/tile) -> stage split into Bu0/Bu1
#pragma unroll
  for (int i = 0; i < 2; ++i) {
    short8 Xa_h = fragr(Xh, i, c15, g), Xa_l = fragr(Xl, i, c15, g);
#pragma unroll
    for (int j = 0; j < 2; ++j) {
      f32x4 a = z4;
      a = MFMA16(Xa_l, S_h[j], a);
      a = MFMA16(Xa_h, S_l[j], a);
      a = MFMA16(Xa_h, S_h[j], a);
      acc[i][j] = a;
    }
  }
  __syncthreads();
#pragma unroll
  for (int i = 0; i < 2; ++i)
#pragma unroll
    for (int j = 0; j < 2; ++j)
      stg_split(Bu0, Bu1, 16 * j + c15, 16 * i + 4 * g, acc[i][j]);
  __syncthreads();
  // 3. Y = S * V2 -> Ytilde
#pragma unroll
  for (int j = 0; j < 2; ++j) {
    short8 Bh = fragr(Bu0, j, c15, g), Bl = fragr(Bu1, j, c15, g);
#pragma unroll
    for (int i = 0; i < 2; ++i) {
      f32x4 a = z4;
      a = MFMA16(S_l[i], Bh, a);
      a = MFMA16(S_h[i], Bl, a);
      a = MFMA16(S_h[i], Bh, a);
      acc[i][j] = a;
    }
  }
  const float GSC = 2.f / (CBETA - CALPHA);
  const float MSH = (CALPHA + CBETA) / (CBETA - CALPHA);
  const float c0 = cof[0], c1 = cof[1];
  f32x4 nTm2[2][2], accB[2][2];
#pragma unroll
  for (int i = 0; i < 2; ++i)
#pragma unroll
    for (int j = 0; j < 2; ++j)
#pragma unroll
      for (int r = 0; r < 4; ++r) {
        float dgf = (i == j) ? dg4[r] : 0.f;
        float yt  = fmaf(acc[i][j][r], GSC, -MSH * dgf);   // Ytilde (= T1)
        accB[i][j][r] = yt;
        nTm2[i][j][r] = -dgf;                              // -T0
        float base = ACCUM ? L[i][j][r] : 0.f;
        L[i][j][r]  = fmaf(c1, yt, fmaf(c0, dgf, base));
      }
  __syncthreads();
  // stage A = 2*Ytilde split -> Xh/Xl (X dead); stage B = T1 single -> Bu0
#pragma unroll
  for (int i = 0; i < 2; ++i)
#pragma unroll
    for (int j = 0; j < 2; ++j) {
      f32x4 y2;
#pragma unroll
      for (int r = 0; r < 4; ++r) y2[r] = accB[i][j][r] + accB[i][j][r];
      stg_split(Xh, Xl, 16 * j + c15, 16 * i + 4 * g, y2);
      stg_single(Bu0, 16 * j + c15, 16 * i + 4 * g, accB[i][j]);
    }
  __syncthreads();
  short8 Yh2[2], Yl2[2];
#pragma unroll
  for (int t = 0; t < 2; ++t) { Yh2[t] = fragr(Xh, t, c15, g); Yl2[t] = fragr(Xl, t, c15, g); }
  // 4. T_k = MFMA(2*Ytilde, T_{k-1}, -T_{k-2});  L += c_k T_k   (pairs, ping-pong)
  f32x4 accA[2][2];
#pragma unroll
  for (int kk = 2; kk < NCHEB; kk += 2) {
    const float cka = cof[kk];
#pragma unroll
    for (int j = 0; j < 2; ++j) {
      short8 Bh = fragr(Bu0, j, c15, g);
#pragma unroll
      for (int i = 0; i < 2; ++i) {
        f32x4 a = nTm2[i][j];
        a = MFMA16(Yl2[i], Bh, a);
        a = MFMA16(Yh2[i], Bh, a);
        accA[i][j] = a;
      }
    }
#pragma unroll
    for (int i = 0; i < 2; ++i)
#pragma unroll
      for (int j = 0; j < 2; ++j)
#pragma unroll
        for (int r = 0; r < 4; ++r) {
          L[i][j][r]    = fmaf(cka, accA[i][j][r], L[i][j][r]);
          nTm2[i][j][r] = -accB[i][j][r];
        }
#pragma unroll
    for (int i = 0; i < 2; ++i)
#pragma unroll
      for (int j = 0; j < 2; ++j)
        stg_single(Bu1, 16 * j + c15, 16 * i + 4 * g, accA[i][j]);
    __syncthreads();
    const float ckb = cof[kk + 1];
#pragma unroll
    for (int j = 0; j < 2; ++j) {
      short8 Bh = fragr(Bu1, j, c15, g);
#pragma unroll
      for (int i = 0; i < 2; ++i) {
        f32x4 a = nTm2[i][j];
        a = MFMA16(Yl2[i], Bh, a);
        a = MFMA16(Yh2[i], Bh, a);
        accB[i][j] = a;
      }
    }
#pragma unroll
    for (int i = 0; i < 2; ++i)
#pragma unroll
      for (int j = 0; j < 2; ++j)
#pragma unroll
        for (int r = 0; r < 4; ++r)
          L[i][j][r] = fmaf(ckb, accB[i][j][r], L[i][j][r]);
    if (kk + 2 < NCHEB) {
#pragma unroll
      for (int i = 0; i < 2; ++i)
#pragma unroll
        for (int j = 0; j < 2; ++j) {
#pragma unroll
          for (int r = 0; r < 4; ++r) nTm2[i][j][r] = -accA[i][j][r];
          stg_single(Bu0, 16 * j + c15, 16 * i + 4 * g, accB[i][j]);
        }
      __syncthreads();
    }
  }
}

// ---------- tiny-kernel helpers (single block, 256 threads: 8 row-groups x 32 cols) ----------

__device__ __forceinline__ float dotrow36(const float* Arow, const float* v) {
  float s = 0.f;
#pragma unroll
  for (int j = 0; j < 8; ++j) {
    float4 a = *reinterpret_cast<const float4*>(Arow + 4 * j);
    s = fmaf(a.x, v[4 * j + 0], s);
    s = fmaf(a.y, v[4 * j + 1], s);
    s = fmaf(a.z, v[4 * j + 2], s);
    s = fmaf(a.w, v[4 * j + 3], s);
  }
  return s;
}

// 256-thread 32x32 matmul: tid = 32*h + c, h in 0..7 owns rows 4h..4h+3
__device__ void mm64(float (*D)[LDSW], const float (*A)[LDSW], const float (*Bm)[LDSW], int tid) {
  const int h = tid >> 5, c = tid & 31;
  float bcol[32];
#pragma unroll
  for (int k = 0; k < 32; ++k) bcol[k] = Bm[k][c];
  float o[4];
#pragma unroll
  for (int i = 0; i < 4; ++i) o[i] = dotrow36(&A[4 * h + i][0], bcol);
  __syncthreads();
#pragma unroll
  for (int i = 0; i < 4; ++i) D[4 * h + i][c] = o[i];
  __syncthreads();
}

__device__ void ns_sqrt(LdsMat& Y, LdsMat& Z, LdsMat& Ya, LdsMat& Za, LdsMat T, int tid) {
  const int h = tid >> 5, c = tid & 31;
  for (int it = 0; it < NS_ITERS; ++it) {
    mm64(T, Z, Y, tid);
#pragma unroll
    for (int i = 0; i < 4; ++i) {
      int r = 4 * h + i;
      T[r][c] = ((r == c) ? 1.5f : 0.f) - 0.5f * T[r][c];
    }
    __syncthreads();
    mm64(Ya, Y, T, tid);
    mm64(Za, T, Z, tid);
    LdsMat t1 = Y; Y = Ya; Ya = t1;
    LdsMat t2 = Z; Z = Za; Za = t2;
  }
}

// ---------- kernels ----------

extern "C" __global__ void __launch_bounds__(256)
spdbn_kA(const float* __restrict__ x, float* __restrict__ wsf) {
  const int e  = (blockIdx.x & 3) * 256 + threadIdx.x;
  const int bs = blockIdx.x >> 2;
  float acc = 0.f;
  for (int t = 0; t < 64; ++t)
    acc += x[(size_t)(bs + 1024 * t) * 1024 + e];
  atomicAdd(&wsf[OFF_MEAN0 + e], acc);
}

extern "C" __global__ void __launch_bounds__(256)
spdbn_kS1(float* __restrict__ wsf) {
  __shared__ alignas(16) float W0[32][LDSW], W1[32][LDSW], W2[32][LDSW], W3[32][LDSW], W4[32][LDSW];
  const int tid = threadIdx.x, h = tid >> 5, c = tid & 31;
  float sacc = 0.f;
#pragma unroll
  for (int k = 0; k < 32; ++k) sacc += wsf[OFF_MEAN0 + 33 * k];
  const float cN = sacc / (32.f * (float)BATCH);
  const float scaleA = 32.f / sacc;
#pragma unroll
  for (int i = 0; i < 4; ++i) {
    int r = 4 * h + i;
    W1[r][c] = wsf[OFF_MEAN0 + r * 32 + c] * scaleA;
    W2[r][c] = (r == c) ? 1.f : 0.f;
  }
  __syncthreads();
  LdsMat Y = W1, Z = W2, Ya = W0, Za = W4;
  ns_sqrt(Y, Z, Ya, Za, W3, tid);
  const float sq = sqrtf(cN), rs = rsqrtf(cN);
#pragma unroll
  for (int i = 0; i < 4; ++i) {
    int r = 4 * h + i;
    wsf[OFF_INVS0 + r * 32 + c] = Z[r][c] * rs;
    wsf[OFF_S0    + r * 32 + c] = Y[r][c] * sq;
  }
  // Chebyshev coefficients of log(t) on [CALPHA, CBETA] (first wave only)
  if (tid < 64) {
    const float PIF = 3.14159265358979f;
    const float th = ((float)tid + 0.5f) * (PIF / 64.f);
    const float t  = 0.5f * (CALPHA + CBETA) + 0.5f * (CBETA - CALPHA) * cosf(th);
    const float fl = logf(t);
    for (int j = 0; j < NCHEB; ++j) {
      float v = fl * cosf((float)j * th) * (2.f / 64.f);
#pragma unroll
      for (int off = 32; off >= 1; off >>= 1) v += __shfl_xor(v, off);
      if (tid == 0) wsf[OFF_CHEB + j] = (j == 0) ? 0.5f * v : v;
    }
  }
}

// Karcher step: accumulate sum_b log(inv_s0 x_b inv_s0)
extern "C" __global__ void __launch_bounds__(64, 3)
spdbn_kB(const float* __restrict__ x, float* __restrict__ wsf) {
  __shared__ alignas(16) u16t Xh[32][40], Xl[32][40], Bu0[32][40], Bu1[32][40];
  const int lane = threadIdx.x;
  const int g = lane >> 4, c15 = lane & 15;
  short8 S_h[2], S_l[2];
  load_sym_frags(wsf + OFF_INVS0, c15, g, S_h, S_l);
  float cof[NCHEB];
#pragma unroll
  for (int k = 0; k < NCHEB; ++k) cof[k] = wsf[OFF_CHEB + k];
  f32x4 dg4;
#pragma unroll
  for (int r = 0; r < 4; ++r) dg4[r] = (4 * g + r == c15) ? 1.f : 0.f;
  f32x4 L[2][2];
#pragma unroll
  for (int i = 0; i < 2; ++i)
#pragma unroll
    for (int j = 0; j < 2; ++j) L[i][j] = (f32x4){0.f, 0.f, 0.f, 0.f};
  for (int b = blockIdx.x; b < BATCH; b += MAIN_BLOCKS) {
    whiten_cheb<true>(x + (size_t)b * 1024, S_h, S_l, Xh, Xl, Bu0, Bu1, cof, g, c15, dg4, L);
    __syncthreads();
  }
#pragma unroll
  for (int i = 0; i < 2; ++i)
#pragma unroll
    for (int j = 0; j < 2; ++j)
#pragma unroll
      for (int r = 0; r < 4; ++r)
        atomicAdd(&wsf[OFF_LOGAVG + (16 * i + 4 * g + r) * 32 + 16 * j + c15], L[i][j][r]);
}

extern "C" __global__ void __launch_bounds__(256)
spdbn_kS2(float* __restrict__ wsf, const float* __restrict__ shift) {
  __shared__ alignas(16) float W0[32][LDSW], W1[32][LDSW], W2[32][LDSW], W3[32][LDSW], W4[32][LDSW];
  const int tid = threadIdx.x, h = tid >> 5, c = tid & 31;
#pragma unroll
  for (int i = 0; i < 4; ++i) {
    int r = 4 * h + i;
    W0[r][c] = wsf[OFF_LOGAVG + r * 32 + c] * (1.f / (float)BATCH);
    W1[r][c] = (r == c) ? 1.f : 0.f;
  }
  __syncthreads();
  for (int j = EXP_TERMS; j >= 1; --j) {       // exp(LA), ||LA|| small -> 8 terms exact
    mm64(W3, W0, W1, tid);
    const float inv = 1.f / (float)j;
#pragma unroll
    for (int i = 0; i < 4; ++i) {
      int r = 4 * h + i;
      W1[r][c] = ((r == c) ? 1.f : 0.f) + W3[r][c] * inv;
    }
    __syncthreads();
  }
#pragma unroll
  for (int i = 0; i < 4; ++i) { int r = 4 * h + i; W2[r][c] = wsf[OFF_S0 + r * 32 + c]; }
  __syncthreads();
  mm64(W3, W2, W1, tid);
  mm64(W0, W3, W2, tid);
  float tr = 0.f;
#pragma unroll
  for (int k = 0; k < 32; ++k) tr += W0[k][k];
  tr *= (1.f / 32.f);
  const float itr = 1.f / tr;
#pragma unroll
  for (int i = 0; i < 4; ++i) {
    int r = 4 * h + i;
    W1[r][c] = W0[r][c] * itr;
    W2[r][c] = (r == c) ? 1.f : 0.f;
  }
  __syncthreads();
  LdsMat Y = W1, Z = W2, Ya = W0, Za = W4;
  ns_sqrt(Y, Z, Ya, Za, W3, tid);
  const float rs = rsqrtf(tr);
#pragma unroll
  for (int i = 0; i < 4; ++i) { int r = 4 * h + i; wsf[OFF_INVS + r * 32 + c] = Z[r][c] * rs; }
  __syncthreads();
  float tr2 = 0.f;
#pragma unroll
  for (int k = 0; k < 32; ++k) tr2 += shift[33 * k];
  tr2 *= (1.f / 32.f);
  const float itr2 = 1.f / tr2;
#pragma unroll
  for (int i = 0; i < 4; ++i) {
    int r = 4 * h + i;
    W1[r][c] = shift[r * 32 + c] * itr2;
    W2[r][c] = (r == c) ? 1.f : 0.f;
  }
  __syncthreads();
  LdsMat Y2 = W1, Z2 = W2, Ya2 = W0, Za2 = W4;
  ns_sqrt(Y2, Z2, Ya2, Za2, W3, tid);
  const float sq2 = sqrtf(tr2);
#pragma unroll
  for (int i = 0; i < 4; ++i) { int r = 4 * h + i; wsf[OFF_SSQRT + r * 32 + c] = Y2[r][c] * sq2; }
}

// BN whiten: L_b = log(inv_s x_b inv_s) -> d_out (scratch); var += ||L_b||_F^2
extern "C" __global__ void __launch_bounds__(64, 3)
spdbn_kC(const float* __restrict__ x, float* __restrict__ wsf, float* __restrict__ outL) {
  __shared__ alignas(16) u16t Xh[32][40], Xl[32][40], Bu0[32][40], Bu1[32][40];
  const int lane = threadIdx.x;
  const int g = lane >> 4, c15 = lane & 15;
  short8 S_h[2], S_l[2];
  load_sym_frags(wsf + OFF_INVS, c15, g, S_h, S_l);
  float cof[NCHEB];
#pragma unroll
  for (int k = 0; k < NCHEB; ++k) cof[k] = wsf[OFF_CHEB + k];
  f32x4 dg4;
#pragma unroll
  for (int r = 0; r < 4; ++r) dg4[r] = (4 * g + r == c15) ? 1.f : 0.f;
  float ss = 0.f;
  f32x4 L[2][2];
  for (int b = blockIdx.x; b < BATCH; b += MAIN_BLOCKS) {
    whiten_cheb<false>(x + (size_t)b * 1024, S_h, S_l, Xh, Xl, Bu0, Bu1, cof, g, c15, dg4, L);
    float* ob = outL + (size_t)b * 1024;
#pragma unroll
    for (int i = 0; i < 2; ++i)
#pragma unroll
      for (int j = 0; j < 2; ++j)
#pragma unroll
        for (int r = 0; r < 4; ++r) {
          float v = L[i][j][r];
          ob[(16 * i + 4 * g + r) * 32 + 16 * j + c15] = v;
          ss = fmaf(v, v, ss);
        }
    __syncthreads();
  }
#pragma unroll
  for (int off = 32; off >= 1; off >>= 1) ss += __shfl_xor(ss, off);
  if (lane == 0) atomicAdd(&wsf[OFF_VAR], ss);
}

extern "C" __global__ void spdbn_kS3(float* __restrict__ wsf, const float* __restrict__ scale) {
  if (threadIdx.x == 0) {
    float var = wsf[OFF_VAR] * (1.f / (float)BATCH);
    float stdv = sqrtf(var);
    wsf[OFF_P] = scale[0] / (stdv + 1e-5f);
  }
}

// out = s_sqrt * exp(p*L) * s_sqrt  (reads L from d_out, overwrites in place)
extern "C" __global__ void __launch_bounds__(64, 3)
spdbn_kD(float* __restrict__ out, const float* __restrict__ wsf) {
  __shared__ alignas(16) u16t Xh[32][40], Xl[32][40], Bu0[32][40], Bu1[32][40];
  const int lane = threadIdx.x;
  const int g = lane >> 4, c15 = lane & 15;
  short8 Q_h[2], Q_l[2];
  load_sym_frags(wsf + OFF_SSQRT, c15, g, Q_h, Q_l);
  const float p = wsf[OFF_P];
  const f32x4 z4 = {0.f, 0.f, 0.f, 0.f};
  f32x4 dg4;
#pragma unroll
  for (int r = 0; r < 4; ++r) dg4[r] = (4 * g + r == c15) ? 1.f : 0.f;
  uint2 idp; idp.x = pack2_rn(dg4[0], dg4[1]); idp.y = pack2_rn(dg4[2], dg4[3]);
  uint2 zp;  zp.x = 0u; zp.y = 0u;
  for (int b = blockIdx.x; b < BATCH; b += MAIN_BLOCKS) {
    float* ob = out + (size_t)b * 1024;
    // stage M = p*L split -> Xh/Xl
#pragma unroll
    for (int e = 0; e < 4; ++e) {
      int idx = e * 256 + lane * 4;
      float4 v = *reinterpret_cast<const float4*>(ob + idx);
      int row = idx >> 5, col = idx & 31;
      u32t h0, l0, h1, l1;
      split2(v.x * p, v.y * p, h0, l0);
      split2(v.z * p, v.w * p, h1, l1);
      uint2 hv; hv.x = h0; hv.y = h1;
      uint2 lv; lv.x = l0; lv.y = l1;
      *reinterpret_cast<uint2*>(&Xh[row][col]) = hv;
      *reinterpret_cast<uint2*>(&Xl[row][col]) = lv;
    }
    // P = I staged single-bf16 into Bu0
#pragma unroll
    for (int i = 0; i < 2; ++i)
#pragma unroll
      for (int j = 0; j < 2; ++j)
        *reinterpret_cast<uint2*>(&Bu0[16 * j + c15][16 * i + 4 * g]) = (i == j) ? idp : zp;
    __syncthreads();
    short8 Mh[2], Ml[2];
#pragma unroll
    for (int t = 0; t < 2; ++t) { Mh[t] = fragr(Xh, t, c15, g); Ml[t] = fragr(Xl, t, c15, g); }
    // Taylor: P = I + (M/jj) P, jj = EXP_TERMS..2 (single-bf16 B, split M)
    f32x4 acc[2][2];
#pragma unroll
    for (int jj = EXP_TERMS; jj >= 2; --jj) {
      const int t = EXP_TERMS - jj;
      const u16t (*R)[40] = (t & 1) ? Bu1 : Bu0;
      u16t (*W)[40]       = (t & 1) ? Bu0 : Bu1;
#pragma unroll
      for (int j = 0; j < 2; ++j) {
        short8 Bh = fragr(R, j, c15, g);
#pragma unroll
        for (int i = 0; i < 2; ++i) {
          f32x4 a = z4;
          a = MFMA16(Ml[i], Bh, a);
          a = MFMA16(Mh[i], Bh, a);
          acc[i][j] = a;
        }
      }
      const float inv = 1.f / (float)jj;
      __syncthreads();
#pragma unroll
      for (int i = 0; i < 2; ++i)
#pragma unroll
        for (int j = 0; j < 2; ++j) {
          f32x4 v;
#pragma unroll
          for (int r = 0; r < 4; ++r)
            v[r] = fmaf(acc[i][j][r], inv, ((16 * i + 4 * g + r) == (16 * j + c15)) ? 1.f : 0.f);
          stg_single(W, 16 * j + c15, 16 * i + 4 * g, v);
        }
      __syncthreads();
    }
    // final jj=1 in f32: Pf = I + M*P  (read Bu1: EXP_TERMS even -> last write was Bu1)
#pragma unroll
    for (int j = 0; j < 2; ++j) {
      short8 Bh = fragr(Bu1, j, c15, g);
#pragma unroll
      for (int i = 0; i < 2; ++i) {
        f32x4 a = z4;
        a = MFMA16(Ml[i], Bh, a);
        a = MFMA16(Mh[i], Bh, a);
        acc[i][j] = a;
      }
    }
    __syncthreads();
#pragma unroll
    for (int i = 0; i < 2; ++i)
#pragma unroll
      for (int j = 0; j < 2; ++j) {
        f32x4 v;
#pragma unroll
        for (int r = 0; r < 4; ++r)
          v[r] = acc[i][j][r] + (((16 * i + 4 * g + r) == (16 * j + c15)) ? 1.f : 0.f);
        stg_split(Xh, Xl, 16 * j + c15, 16 * i + 4 * g, v);
      }
    __syncthreads();
    short8 Ph[2], Pl[2];
#pragma unroll
    for (int t = 0; t < 2; ++t) { Ph[t] = fragr(Xh, t, c15, g); Pl[t] = fragr(Xl, t, c15, g); }
    // W = P * Ssq (split x split) -> stage split -> Bu0/Bu1
#pragma unroll
    for (int i = 0; i < 2; ++i)
#pragma unroll
      for (int j = 0; j < 2; ++j) {
        f32x4 a = z4;
        a = MFMA16(Pl[i], Q_h[j], a);
        a = MFMA16(Ph[i], Q_l[j], a);
        a = MFMA16(Ph[i], Q_h[j], a);
        acc[i][j] = a;
      }
    __syncthreads();
#pragma unroll
    for (int i = 0; i < 2; ++i)
#pragma unroll
      for (int j = 0; j < 2; ++j)
        stg_split(Bu0, Bu1, 16 * j + c15, 16 * i + 4 * g, acc[i][j]);
    __syncthreads();
    // out = Ssq * W
#pragma unroll
    for (int j = 0; j < 2; ++j) {
      short8 Wh = fragr(Bu0, j, c15, g), Wl = fragr(Bu1, j, c15, g);
#pragma unroll
      for (int i = 0; i < 2; ++i) {
        f32x4 a = z4;
        a = MFMA16(Q_l[i], Wh, a);
        a = MFMA16(Q_h[i], Wl, a);
        a = MFMA16(Q_h[i], Wh, a);
        acc[i][j] = a;
      }
    }
#pragma unroll
    for (int i = 0; i < 2; ++i)
#pragma unroll
      for (int j = 0; j < 2; ++j)
#pragma unroll
        for (int r = 0; r < 4; ++r)
          ob[(16 * i + 4 * g + r) * 32 + 16 * j + c15] = acc[i][j][r];
    __syncthreads();
  }
}

extern "C" void kernel_launch(void* const* d_in, const int* in_sizes, int n_in,
                              void* d_out, int out_size, void* d_ws, size_t ws_size,
                              hipStream_t stream) {
  const float* x     = (const float*)d_in[0];
  const float* shift = (const float*)d_in[1];
  const float* scale = (const float*)d_in[2];
  float* out = (float*)d_out;
  float* wsf = (float*)d_ws;

  size_t zbytes = 32768;
  if (ws_size < zbytes) zbytes = ws_size;
  hipMemsetAsync(d_ws, 0, zbytes, stream);

  hipLaunchKernelGGL(spdbn_kA,  dim3(4096), dim3(256), 0, stream, x, wsf);
  hipLaunchKernelGGL(spdbn_kS1, dim3(1),    dim3(256), 0, stream, wsf);
  hipLaunchKernelGGL(spdbn_kB,  dim3(MAIN_BLOCKS), dim3(64), 0, stream, x, wsf);
  hipLaunchKernelGGL(spdbn_kS2, dim3(1),    dim3(256), 0, stream, wsf, shift);
  hipLaunchKernelGGL(spdbn_kC,  dim3(MAIN_BLOCKS), dim3(64), 0, stream, x, wsf, out);
  hipLaunchKernelGGL(spdbn_kS3, dim3(1),    dim3(64),  0, stream, wsf, scale);
  hipLaunchKernelGGL(spdbn_kD,  dim3(MAIN_BLOCKS), dim3(64), 0, stream, out, wsf);
}

// Round 11
// 671.685 us; speedup vs baseline: 2.9401x; 1.0424x over previous
//
#include <hip/hip_runtime.h>
#include <cstdint>
#include <cstddef>

#define BATCH       65536
#define LDSW        36          // padded LDS row stride for tiny-kernel matrices
#define NCHEB       16          // Chebyshev terms on [CALPHA, CBETA] (validated r7/r8)
#define CALPHA      0.28f
#define CBETA       4.6f
#define NS_ITERS    4
#define EXP_TERMS   8
#define MAIN_BLOCKS 3072        // kD grid (unchanged r9 path)
#define GRID_BC     4096        // kB/kC: LDS-free, VGPR-limited -> up to 16/CU

// ws float offsets
#define OFF_MEAN0   0
#define OFF_INVS0   1024
#define OFF_S0      2048
#define OFF_LOGAVG  3072
#define OFF_INVS    4096
#define OFF_SSQRT   5120
#define OFF_VAR     6144
#define OFF_P       6145
#define OFF_CHEB    6152

typedef float (*LdsMat)[LDSW];
typedef __attribute__((ext_vector_type(8)))  short short8;
typedef __attribute__((ext_vector_type(4)))  float f32x4;
typedef __attribute__((ext_vector_type(16))) float f32x16;
typedef unsigned short u16t;
typedef unsigned int   u32t;

#define MFMA16(a, b, c) __builtin_amdgcn_mfma_f32_16x16x32_bf16((a), (b), (c), 0, 0, 0)
#define MFMA32(a, b, c) __builtin_amdgcn_mfma_f32_32x32x16_bf16((a), (b), (c), 0, 0, 0)

// ---------------- bf16 pack / split helpers (perm-based, proven r4-r9) ----------------
__device__ __forceinline__ u32t pack2_rn(float a, float b) {
  u32t ua = __float_as_uint(a) + 0x8000u;
  u32t ub = __float_as_uint(b) + 0x8000u;
  return __builtin_amdgcn_perm(ub, ua, 0x07060302u);
}
__device__ __forceinline__ void split2(float a, float b, u32t& hw, u32t& lw) {
  u32t ua = __float_as_uint(a) + 0x8000u;
  u32t ub = __float_as_uint(b) + 0x8000u;
  hw = __builtin_amdgcn_perm(ub, ua, 0x07060302u);
  float ra = a - __uint_as_float(ua & 0xFFFF0000u);
  float rb = b - __uint_as_float(ub & 0xFFFF0000u);
  lw = __builtin_amdgcn_perm(__float_as_uint(rb), __float_as_uint(ra), 0x07060302u);
}
__device__ __forceinline__ void split8regs(float4 a, float4 b, float mul, short8& hi, short8& lo) {
  u32t h0, l0, h1, l1, h2, l2, h3, l3;
  split2(a.x * mul, a.y * mul, h0, l0);
  split2(a.z * mul, a.w * mul, h1, l1);
  split2(b.x * mul, b.y * mul, h2, l2);
  split2(b.z * mul, b.w * mul, h3, l3);
  union { uint4 u; short8 s; } uh, ul;
  uh.u.x = h0; uh.u.y = h1; uh.u.z = h2; uh.u.w = h3;
  ul.u.x = l0; ul.u.y = l1; ul.u.z = l2; ul.u.w = l3;
  hi = uh.s; lo = ul.s;
}
__device__ __forceinline__ void splitf(float a, u16t& h, u16t& l) {
  unsigned u  = __float_as_uint(a);
  unsigned uh = (u + 0x8000u) & 0xFFFF0000u;
  float    r  = a - __uint_as_float(uh);
  unsigned ul = __float_as_uint(r) + 0x8000u;
  h = (u16t)(uh >> 16);
  l = (u16t)(ul >> 16);
}

// ---------------- 32x32 register-exchange helpers (FIXED swap wiring) ----------------
// C-layout (32x32): lane = 32q + n holds D[row=(rr&3)+8(rr>>2)+4q][col=n], rr=0..15.
// B-frag (32x32x16, K-tile t): lane needs B[k=16t+8q+j][n], j=0..7.
// v_permlane32_swap_b32(vdst,vsrc) semantics (CDNA4): DST.row1 <-> SRC.row0, i.e.
//   ret[0] = new vdst = { vdst[0:31] | vsrc[0:31] moved to lanes 32-63 }
//   ret[1] = new vsrc = { vdst[32:63] moved to lanes 0-31 | vsrc[32:63] }
// (r10 coded the opposite direction -> structured finite error; rewired here.)
// Wiring: r = swap(w_even_lo, w_even_hi); low-k dword = r[0], high-k dword = r[1].
__device__ __forceinline__ void cmaj_to_bfrag(const f32x16& v, short8& f0, short8& f1) {
  u32t w[8];
#pragma unroll
  for (int d = 0; d < 8; ++d) w[d] = pack2_rn(v[2 * d], v[2 * d + 1]);
  auto r02 = __builtin_amdgcn_permlane32_swap(w[0], w[2], false, false);
  auto r13 = __builtin_amdgcn_permlane32_swap(w[1], w[3], false, false);
  auto r46 = __builtin_amdgcn_permlane32_swap(w[4], w[6], false, false);
  auto r57 = __builtin_amdgcn_permlane32_swap(w[5], w[7], false, false);
  union { uint4 u; short8 s; } A, B;
  A.u.x = r02[0]; A.u.y = r13[0]; A.u.z = r02[1]; A.u.w = r13[1];
  B.u.x = r46[0]; B.u.y = r57[0]; B.u.z = r46[1]; B.u.w = r57[1];
  f0 = A.s; f1 = B.s;
}
__device__ __forceinline__ void cmaj_to_bfrag_split(const f32x16& v,
    short8& f0h, short8& f1h, short8& f0l, short8& f1l) {
  u32t wh[8], wl[8];
#pragma unroll
  for (int d = 0; d < 8; ++d) split2(v[2 * d], v[2 * d + 1], wh[d], wl[d]);
  {
    auto r02 = __builtin_amdgcn_permlane32_swap(wh[0], wh[2], false, false);
    auto r13 = __builtin_amdgcn_permlane32_swap(wh[1], wh[3], false, false);
    auto r46 = __builtin_amdgcn_permlane32_swap(wh[4], wh[6], false, false);
    auto r57 = __builtin_amdgcn_permlane32_swap(wh[5], wh[7], false, false);
    union { uint4 u; short8 s; } A, B;
    A.u.x = r02[0]; A.u.y = r13[0]; A.u.z = r02[1]; A.u.w = r13[1];
    B.u.x = r46[0]; B.u.y = r57[0]; B.u.z = r46[1]; B.u.w = r57[1];
    f0h = A.s; f1h = B.s;
  }
  {
    auto r02 = __builtin_amdgcn_permlane32_swap(wl[0], wl[2], false, false);
    auto r13 = __builtin_amdgcn_permlane32_swap(wl[1], wl[3], false, false);
    auto r46 = __builtin_amdgcn_permlane32_swap(wl[4], wl[6], false, false);
    auto r57 = __builtin_amdgcn_permlane32_swap(wl[5], wl[7], false, false);
    union { uint4 u; short8 s; } A, B;
    A.u.x = r02[0]; A.u.y = r13[0]; A.u.z = r02[1]; A.u.w = r13[1];
    B.u.x = r46[0]; B.u.y = r57[0]; B.u.z = r46[1]; B.u.w = r57[1];
    f0l = A.s; f1l = B.s;
  }
}
// Cold: load symmetric 32x32 f32 -> A/B frags (row n, k = 16t+8q+j)
__device__ __forceinline__ void load_sym_frags32(const float* base, int n, int q,
                                                 short8* Fh, short8* Fl) {
#pragma unroll
  for (int t = 0; t < 2; ++t) {
    const float* sp = base + n * 32 + 16 * t + 8 * q;
    short8 hh, ll;
#pragma unroll
    for (int j = 0; j < 8; ++j) {
      u16t h, l;
      splitf(sp[j], h, l);
      hh[j] = (short)h;
      ll[j] = (short)l;
    }
    Fh[t] = hh;
    Fl[t] = ll;
  }
}

// ---------------- register-only whiten + forward-Chebyshev log (32x32 MFMA) ----------------
// L = cheb_log( GSC*(S x S) - MSH*I ), all operand exchange via permlane32_swap; zero LDS.
template <bool ACCUM>
__device__ __forceinline__ void whiten_cheb32(
    const float* __restrict__ xb, const short8* S_h, const short8* S_l,
    const float* __restrict__ cof, int q, int n, f32x16& L) {
  f32x16 z16;
#pragma unroll
  for (int rr = 0; rr < 16; ++rr) z16[rr] = 0.f;
  // 1. X A-frags direct from global (X symmetric)
  short8 Xh[2], Xl[2];
#pragma unroll
  for (int t = 0; t < 2; ++t) {
    const float* p = xb + n * 32 + 16 * t + 8 * q;
    float4 a = *reinterpret_cast<const float4*>(p);
    float4 b = *reinterpret_cast<const float4*>(p + 4);
    split8regs(a, b, 1.f, Xh[t], Xl[t]);
  }
  // 2. V2 = X * S
  f32x16 v2 = z16;
#pragma unroll
  for (int t = 0; t < 2; ++t) {
    v2 = MFMA32(Xl[t], S_h[t], v2);
    v2 = MFMA32(Xh[t], S_l[t], v2);
    v2 = MFMA32(Xh[t], S_h[t], v2);
  }
  // 3. V2 B-frags (split) in registers
  short8 Vh[2], Vl[2];
  cmaj_to_bfrag_split(v2, Vh[0], Vh[1], Vl[0], Vl[1]);
  // 4. Y = S * V2
  f32x16 y = z16;
#pragma unroll
  for (int t = 0; t < 2; ++t) {
    y = MFMA32(S_l[t], Vh[t], y);
    y = MFMA32(S_h[t], Vl[t], y);
    y = MFMA32(S_h[t], Vh[t], y);
  }
  // 5. T1 = GSC*Y - MSH*I ; init L, nTm2
  const float GSC = 2.f / (CBETA - CALPHA);
  const float MSH = (CALPHA + CBETA) / (CBETA - CALPHA);
  const float c0 = cof[0], c1 = cof[1];
  f32x16 accB, nTm2;
#pragma unroll
  for (int rr = 0; rr < 16; ++rr) {
    int row = (rr & 3) + 8 * (rr >> 2) + 4 * q;
    float dgf = (row == n) ? 1.f : 0.f;
    float t1 = fmaf(y[rr], GSC, -MSH * dgf);
    accB[rr] = t1;
    nTm2[rr] = -dgf;
    float base = ACCUM ? L[rr] : 0.f;
    L[rr] = fmaf(c1, t1, fmaf(c0, dgf, base));
  }
  // A-frags of 2*Ytilde (symmetric) split
  f32x16 y2 = accB + accB;
  short8 Yh[2], Yl[2];
  cmaj_to_bfrag_split(y2, Yh[0], Yh[1], Yl[0], Yl[1]);
  // 6. T_k = MFMA(2Yt, bf16(T_{k-1}), -T_{k-2}); L += c_k T_k   (register-only)
#pragma unroll
  for (int k = 2; k < NCHEB; ++k) {
    short8 B0, B1;
    cmaj_to_bfrag(accB, B0, B1);
    f32x16 acc = nTm2;
    acc = MFMA32(Yl[0], B0, acc);
    acc = MFMA32(Yh[0], B0, acc);
    acc = MFMA32(Yl[1], B1, acc);
    acc = MFMA32(Yh[1], B1, acc);
    const float ck = cof[k];
#pragma unroll
    for (int rr = 0; rr < 16; ++rr) {
      L[rr]    = fmaf(ck, acc[rr], L[rr]);
      nTm2[rr] = -accB[rr];
    }
    accB = acc;
  }
}

// ---------------- 16x16 LDS helpers (kD path, r9-proven, unchanged) ----------------
__device__ __forceinline__ short8 fragr(const u16t (*G)[40], int t, int c15, int g) {
  return *reinterpret_cast<const short8*>(&G[16 * t + c15][8 * g]);
}
__device__ __forceinline__ void stg_single(u16t (*G)[40], int col, int row, f32x4 v) {
  uint2 w; w.x = pack2_rn(v[0], v[1]); w.y = pack2_rn(v[2], v[3]);
  *reinterpret_cast<uint2*>(&G[col][row]) = w;
}
__device__ __forceinline__ void stg_split(u16t (*Gh)[40], u16t (*Gl)[40], int col, int row, f32x4 v) {
  u32t h0, l0, h1, l1;
  split2(v[0], v[1], h0, l0);
  split2(v[2], v[3], h1, l1);
  uint2 hv; hv.x = h0; hv.y = h1;
  uint2 lv; lv.x = l0; lv.y = l1;
  *reinterpret_cast<uint2*>(&Gh[col][row]) = hv;
  *reinterpret_cast<uint2*>(&Gl[col][row]) = lv;
}
__device__ __forceinline__ void load_sym_frags(const float* base, int c15, int g,
                                               short8* Fh, short8* Fl) {
#pragma unroll
  for (int t = 0; t < 2; ++t) {
    const float* sp = base + (16 * t + c15) * 32 + 8 * g;
    short8 hh, ll;
#pragma unroll
    for (int j = 0; j < 8; ++j) {
      u16t h, l;
      splitf(sp[j], h, l);
      hh[j] = (short)h;
      ll[j] = (short)l;
    }
    Fh[t] = hh;
    Fl[t] = ll;
  }
}

// ---------- tiny-kernel helpers (single block, 256 threads; r9-proven) ----------
__device__ __forceinline__ float dotrow36(const float* Arow, const float* v) {
  float s = 0.f;
#pragma unroll
  for (int j = 0; j < 8; ++j) {
    float4 a = *reinterpret_cast<const float4*>(Arow + 4 * j);
    s = fmaf(a.x, v[4 * j + 0], s);
    s = fmaf(a.y, v[4 * j + 1], s);
    s = fmaf(a.z, v[4 * j + 2], s);
    s = fmaf(a.w, v[4 * j + 3], s);
  }
  return s;
}
__device__ void mm64(float (*D)[LDSW], const float (*A)[LDSW], const float (*Bm)[LDSW], int tid) {
  const int h = tid >> 5, c = tid & 31;
  float bcol[32];
#pragma unroll
  for (int k = 0; k < 32; ++k) bcol[k] = Bm[k][c];
  float o[4];
#pragma unroll
  for (int i = 0; i < 4; ++i) o[i] = dotrow36(&A[4 * h + i][0], bcol);
  __syncthreads();
#pragma unroll
  for (int i = 0; i < 4; ++i) D[4 * h + i][c] = o[i];
  __syncthreads();
}
__device__ void ns_sqrt(LdsMat& Y, LdsMat& Z, LdsMat& Ya, LdsMat& Za, LdsMat T, int tid) {
  const int h = tid >> 5, c = tid & 31;
  for (int it = 0; it < NS_ITERS; ++it) {
    mm64(T, Z, Y, tid);
#pragma unroll
    for (int i = 0; i < 4; ++i) {
      int r = 4 * h + i;
      T[r][c] = ((r == c) ? 1.5f : 0.f) - 0.5f * T[r][c];
    }
    __syncthreads();
    mm64(Ya, Y, T, tid);
    mm64(Za, T, Z, tid);
    LdsMat t1 = Y; Y = Ya; Ya = t1;
    LdsMat t2 = Z; Z = Za; Za = t2;
  }
}

// ---------- kernels ----------

extern "C" __global__ void __launch_bounds__(256)
spdbn_kA(const float* __restrict__ x, float* __restrict__ wsf) {
  const int e  = (blockIdx.x & 3) * 256 + threadIdx.x;
  const int bs = blockIdx.x >> 2;
  float acc = 0.f;
  for (int t = 0; t < 64; ++t)
    acc += x[(size_t)(bs + 1024 * t) * 1024 + e];
  atomicAdd(&wsf[OFF_MEAN0 + e], acc);
}

extern "C" __global__ void __launch_bounds__(256)
spdbn_kS1(float* __restrict__ wsf) {
  __shared__ alignas(16) float W0[32][LDSW], W1[32][LDSW], W2[32][LDSW], W3[32][LDSW], W4[32][LDSW];
  const int tid = threadIdx.x, h = tid >> 5, c = tid & 31;
  float sacc = 0.f;
#pragma unroll
  for (int k = 0; k < 32; ++k) sacc += wsf[OFF_MEAN0 + 33 * k];
  const float cN = sacc / (32.f * (float)BATCH);
  const float scaleA = 32.f / sacc;
#pragma unroll
  for (int i = 0; i < 4; ++i) {
    int r = 4 * h + i;
    W1[r][c] = wsf[OFF_MEAN0 + r * 32 + c] * scaleA;
    W2[r][c] = (r == c) ? 1.f : 0.f;
  }
  __syncthreads();
  LdsMat Y = W1, Z = W2, Ya = W0, Za = W4;
  ns_sqrt(Y, Z, Ya, Za, W3, tid);
  const float sq = sqrtf(cN), rs = rsqrtf(cN);
#pragma unroll
  for (int i = 0; i < 4; ++i) {
    int r = 4 * h + i;
    wsf[OFF_INVS0 + r * 32 + c] = Z[r][c] * rs;
    wsf[OFF_S0    + r * 32 + c] = Y[r][c] * sq;
  }
  if (tid < 64) {
    const float PIF = 3.14159265358979f;
    const float th = ((float)tid + 0.5f) * (PIF / 64.f);
    const float t  = 0.5f * (CALPHA + CBETA) + 0.5f * (CBETA - CALPHA) * cosf(th);
    const float fl = logf(t);
    for (int j = 0; j < NCHEB; ++j) {
      float v = fl * cosf((float)j * th) * (2.f / 64.f);
#pragma unroll
      for (int off = 32; off >= 1; off >>= 1) v += __shfl_xor(v, off);
      if (tid == 0) wsf[OFF_CHEB + j] = (j == 0) ? 0.5f * v : v;
    }
  }
}

// Karcher step: accumulate sum_b log(inv_s0 x_b inv_s0)   [register-only core]
extern "C" __global__ void __launch_bounds__(64, 3)
spdbn_kB(const float* __restrict__ x, float* __restrict__ wsf) {
  const int lane = threadIdx.x, q = lane >> 5, n = lane & 31;
  short8 S_h[2], S_l[2];
  load_sym_frags32(wsf + OFF_INVS0, n, q, S_h, S_l);
  float cof[NCHEB];
#pragma unroll
  for (int k = 0; k < NCHEB; ++k) cof[k] = wsf[OFF_CHEB + k];
  f32x16 L;
#pragma unroll
  for (int rr = 0; rr < 16; ++rr) L[rr] = 0.f;
  for (int b = blockIdx.x; b < BATCH; b += gridDim.x)
    whiten_cheb32<true>(x + (size_t)b * 1024, S_h, S_l, cof, q, n, L);
#pragma unroll
  for (int rr = 0; rr < 16; ++rr)
    atomicAdd(&wsf[OFF_LOGAVG + ((rr & 3) + 8 * (rr >> 2) + 4 * q) * 32 + n], L[rr]);
}

extern "C" __global__ void __launch_bounds__(256)
spdbn_kS2(float* __restrict__ wsf, const float* __restrict__ shift) {
  __shared__ alignas(16) float W0[32][LDSW], W1[32][LDSW], W2[32][LDSW], W3[32][LDSW], W4[32][LDSW];
  const int tid = threadIdx.x, h = tid >> 5, c = tid & 31;
#pragma unroll
  for (int i = 0; i < 4; ++i) {
    int r = 4 * h + i;
    W0[r][c] = wsf[OFF_LOGAVG + r * 32 + c] * (1.f / (float)BATCH);
    W1[r][c] = (r == c) ? 1.f : 0.f;
  }
  __syncthreads();
  for (int j = EXP_TERMS; j >= 1; --j) {
    mm64(W3, W0, W1, tid);
    const float inv = 1.f / (float)j;
#pragma unroll
    for (int i = 0; i < 4; ++i) {
      int r = 4 * h + i;
      W1[r][c] = ((r == c) ? 1.f : 0.f) + W3[r][c] * inv;
    }
    __syncthreads();
  }
#pragma unroll
  for (int i = 0; i < 4; ++i) { int r = 4 * h + i; W2[r][c] = wsf[OFF_S0 + r * 32 + c]; }
  __syncthreads();
  mm64(W3, W2, W1, tid);
  mm64(W0, W3, W2, tid);
  float tr = 0.f;
#pragma unroll
  for (int k = 0; k < 32; ++k) tr += W0[k][k];
  tr *= (1.f / 32.f);
  const float itr = 1.f / tr;
#pragma unroll
  for (int i = 0; i < 4; ++i) {
    int r = 4 * h + i;
    W1[r][c] = W0[r][c] * itr;
    W2[r][c] = (r == c) ? 1.f : 0.f;
  }
  __syncthreads();
  LdsMat Y = W1, Z = W2, Ya = W0, Za = W4;
  ns_sqrt(Y, Z, Ya, Za, W3, tid);
  const float rs = rsqrtf(tr);
#pragma unroll
  for (int i = 0; i < 4; ++i) { int r = 4 * h + i; wsf[OFF_INVS + r * 32 + c] = Z[r][c] * rs; }
  __syncthreads();
  float tr2 = 0.f;
#pragma unroll
  for (int k = 0; k < 32; ++k) tr2 += shift[33 * k];
  tr2 *= (1.f / 32.f);
  const float itr2 = 1.f / tr2;
#pragma unroll
  for (int i = 0; i < 4; ++i) {
    int r = 4 * h + i;
    W1[r][c] = shift[r * 32 + c] * itr2;
    W2[r][c] = (r == c) ? 1.f : 0.f;
  }
  __syncthreads();
  LdsMat Y2 = W1, Z2 = W2, Ya2 = W0, Za2 = W4;
  ns_sqrt(Y2, Z2, Ya2, Za2, W3, tid);
  const float sq2 = sqrtf(tr2);
#pragma unroll
  for (int i = 0; i < 4; ++i) { int r = 4 * h + i; wsf[OFF_SSQRT + r * 32 + c] = Y2[r][c] * sq2; }
}

// BN whiten: L_b -> d_out (scratch); var += ||L_b||_F^2   [register-only core]
extern "C" __global__ void __launch_bounds__(64, 3)
spdbn_kC(const float* __restrict__ x, float* __restrict__ wsf, float* __restrict__ outL) {
  const int lane = threadIdx.x, q = lane >> 5, n = lane & 31;
  short8 S_h[2], S_l[2];
  load_sym_frags32(wsf + OFF_INVS, n, q, S_h, S_l);
  float cof[NCHEB];
#pragma unroll
  for (int k = 0; k < NCHEB; ++k) cof[k] = wsf[OFF_CHEB + k];
  float ss = 0.f;
  f32x16 L;
  for (int b = blockIdx.x; b < BATCH; b += gridDim.x) {
    whiten_cheb32<false>(x + (size_t)b * 1024, S_h, S_l, cof, q, n, L);
    float* ob = outL + (size_t)b * 1024;
#pragma unroll
    for (int rr = 0; rr < 16; ++rr) {
      float v = L[rr];
      ob[((rr & 3) + 8 * (rr >> 2) + 4 * q) * 32 + n] = v;
      ss = fmaf(v, v, ss);
    }
  }
#pragma unroll
  for (int off = 32; off >= 1; off >>= 1) ss += __shfl_xor(ss, off);
  if (lane == 0) atomicAdd(&wsf[OFF_VAR], ss);
}

extern "C" __global__ void spdbn_kS3(float* __restrict__ wsf, const float* __restrict__ scale) {
  if (threadIdx.x == 0) {
    float var = wsf[OFF_VAR] * (1.f / (float)BATCH);
    float stdv = sqrtf(var);
    wsf[OFF_P] = scale[0] / (stdv + 1e-5f);
  }
}

// out = s_sqrt * exp(p*L) * s_sqrt  (r9-proven path, unchanged)
extern "C" __global__ void __launch_bounds__(64, 3)
spdbn_kD(float* __restrict__ out, const float* __restrict__ wsf) {
  __shared__ alignas(16) u16t Xh[32][40], Xl[32][40], Bu0[32][40], Bu1[32][40];
  const int lane = threadIdx.x;
  const int g = lane >> 4, c15 = lane & 15;
  short8 Q_h[2], Q_l[2];
  load_sym_frags(wsf + OFF_SSQRT, c15, g, Q_h, Q_l);
  const float p = wsf[OFF_P];
  const f32x4 z4 = {0.f, 0.f, 0.f, 0.f};
  f32x4 dg4;
#pragma unroll
  for (int r = 0; r < 4; ++r) dg4[r] = (4 * g + r == c15) ? 1.f : 0.f;
  uint2 idp; idp.x = pack2_rn(dg4[0], dg4[1]); idp.y = pack2_rn(dg4[2], dg4[3]);
  uint2 zp;  zp.x = 0u; zp.y = 0u;
  for (int b = blockIdx.x; b < BATCH; b += MAIN_BLOCKS) {
    float* ob = out + (size_t)b * 1024;
#pragma unroll
    for (int e = 0; e < 4; ++e) {
      int idx = e * 256 + lane * 4;
      float4 v = *reinterpret_cast<const float4*>(ob + idx);
      int row = idx >> 5, col = idx & 31;
      u32t h0, l0, h1, l1;
      split2(v.x * p, v.y * p, h0, l0);
      split2(v.z * p, v.w * p, h1, l1);
      uint2 hv; hv.x = h0; hv.y = h1;
      uint2 lv; lv.x = l0; lv.y = l1;
      *reinterpret_cast<uint2*>(&Xh[row][col]) = hv;
      *reinterpret_cast<uint2*>(&Xl[row][col]) = lv;
    }
#pragma unroll
    for (int i = 0; i < 2; ++i)
#pragma unroll
      for (int j = 0; j < 2; ++j)
        *reinterpret_cast<uint2*>(&Bu0[16 * j + c15][16 * i + 4 * g]) = (i == j) ? idp : zp;
    __syncthreads();
    short8 Mh[2], Ml[2];
#pragma unroll
    for (int t = 0; t < 2; ++t) { Mh[t] = fragr(Xh, t, c15, g); Ml[t] = fragr(Xl, t, c15, g); }
    f32x4 acc[2][2];
#pragma unroll
    for (int jj = EXP_TERMS; jj >= 2; --jj) {
      const int t = EXP_TERMS - jj;
      const u16t (*R)[40] = (t & 1) ? Bu1 : Bu0;
      u16t (*W)[40]       = (t & 1) ? Bu0 : Bu1;
#pragma unroll
      for (int j = 0; j < 2; ++j) {
        short8 Bh = fragr(R, j, c15, g);
#pragma unroll
        for (int i = 0; i < 2; ++i) {
          f32x4 a = z4;
          a = MFMA16(Ml[i], Bh, a);
          a = MFMA16(Mh[i], Bh, a);
          acc[i][j] = a;
        }
      }
      const float inv = 1.f / (float)jj;
      __syncthreads();
#pragma unroll
      for (int i = 0; i < 2; ++i)
#pragma unroll
        for (int j = 0; j < 2; ++j) {
          f32x4 v;
#pragma unroll
          for (int r = 0; r < 4; ++r)
            v[r] = fmaf(acc[i][j][r], inv, ((16 * i + 4 * g + r) == (16 * j + c15)) ? 1.f : 0.f);
          stg_single(W, 16 * j + c15, 16 * i + 4 * g, v);
        }
      __syncthreads();
    }
#pragma unroll
    for (int j = 0; j < 2; ++j) {
      short8 Bh = fragr(Bu1, j, c15, g);
#pragma unroll
      for (int i = 0; i < 2; ++i) {
        f32x4 a = z4;
        a = MFMA16(Ml[i], Bh, a);
        a = MFMA16(Mh[i], Bh, a);
        acc[i][j] = a;
      }
    }
    __syncthreads();
#pragma unroll
    for (int i = 0; i < 2; ++i)
#pragma unroll
      for (int j = 0; j < 2; ++j) {
        f32x4 v;
#pragma unroll
        for (int r = 0; r < 4; ++r)
          v[r] = acc[i][j][r] + (((16 * i + 4 * g + r) == (16 * j + c15)) ? 1.f : 0.f);
        stg_split(Xh, Xl, 16 * j + c15, 16 * i + 4 * g, v);
      }
    __syncthreads();
    short8 Ph[2], Pl[2];
#pragma unroll
    for (int t = 0; t < 2; ++t) { Ph[t] = fragr(Xh, t, c15, g); Pl[t] = fragr(Xl, t, c15, g); }
#pragma unroll
    for (int i = 0; i < 2; ++i)
#pragma unroll
      for (int j = 0; j < 2; ++j) {
        f32x4 a = z4;
        a = MFMA16(Pl[i], Q_h[j], a);
        a = MFMA16(Ph[i], Q_l[j], a);
        a = MFMA16(Ph[i], Q_h[j], a);
        acc[i][j] = a;
      }
    __syncthreads();
#pragma unroll
    for (int i = 0; i < 2; ++i)
#pragma unroll
      for (int j = 0; j < 2; ++j)
        stg_split(Bu0, Bu1, 16 * j + c15, 16 * i + 4 * g, acc[i][j]);
    __syncthreads();
#pragma unroll
    for (int j = 0; j < 2; ++j) {
      short8 Wh = fragr(Bu0, j, c15, g), Wl = fragr(Bu1, j, c15, g);
#pragma unroll
      for (int i = 0; i < 2; ++i) {
        f32x4 a = z4;
        a = MFMA16(Q_l[i], Wh, a);
        a = MFMA16(Q_h[i], Wl, a);
        a = MFMA16(Q_h[i], Wh, a);
        acc[i][j] = a;
      }
    }
#pragma unroll
    for (int i = 0; i < 2; ++i)
#pragma unroll
      for (int j = 0; j < 2; ++j)
#pragma unroll
        for (int r = 0; r < 4; ++r)
          ob[(16 * i + 4 * g + r) * 32 + 16 * j + c15] = acc[i][j][r];
    __syncthreads();
  }
}

extern "C" void kernel_launch(void* const* d_in, const int* in_sizes, int n_in,
                              void* d_out, int out_size, void* d_ws, size_t ws_size,
                              hipStream_t stream) {
  const float* x     = (const float*)d_in[0];
  const float* shift = (const float*)d_in[1];
  const float* scale = (const float*)d_in[2];
  float* out = (float*)d_out;
  float* wsf = (float*)d_ws;

  size_t zbytes = 32768;
  if (ws_size < zbytes) zbytes = ws_size;
  hipMemsetAsync(d_ws, 0, zbytes, stream);

  hipLaunchKernelGGL(spdbn_kA,  dim3(4096),    dim3(256), 0, stream, x, wsf);
  hipLaunchKernelGGL(spdbn_kS1, dim3(1),       dim3(256), 0, stream, wsf);
  hipLaunchKernelGGL(spdbn_kB,  dim3(GRID_BC), dim3(64),  0, stream, x, wsf);
  hipLaunchKernelGGL(spdbn_kS2, dim3(1),       dim3(256), 0, stream, wsf, shift);
  hipLaunchKernelGGL(spdbn_kC,  dim3(GRID_BC), dim3(64),  0, stream, x, wsf, out);
  hipLaunchKernelGGL(spdbn_kS3, dim3(1),       dim3(64),  0, stream, wsf, scale);
  hipLaunchKernelGGL(spdbn_kD,  dim3(MAIN_BLOCKS), dim3(64), 0, stream, out, wsf);
}